// Round 9
// baseline (6516.811 us; speedup 1.0000x reference)
//
#include <hip/hip_runtime.h>

typedef __bf16 bf16x8 __attribute__((ext_vector_type(8)));
typedef float  f32x4  __attribute__((ext_vector_type(4)));

#define Bn  512
#define TM1 63
#define PSTR 76
#define NBLK 512u
#define NLEAF 16u
#define BPL 32u   // blocks per leaf = NBLK/NLEAF

__device__ __forceinline__ float fast_rcp(float x){ return __builtin_amdgcn_rcpf(x); }
__device__ __forceinline__ float fast_tanh(float x){
    float e = __expf(2.0f*x);
    return 1.0f - 2.0f*fast_rcp(e + 1.0f);
}
__device__ __forceinline__ float fast_sigmoid(float x){
    return fast_rcp(1.0f + __expf(-x));
}

// async global->LDS, 16B per lane; lds ptr must be wave-uniform (HW adds lane*16)
__device__ __forceinline__ void gll16(const __bf16* g, __bf16* l) {
    __builtin_amdgcn_global_load_lds(
        (const __attribute__((address_space(1))) unsigned int*)(g),
        (__attribute__((address_space(3))) unsigned int*)(l),
        16, 0, 0);
}

// ---- two-level monotonic grid barrier (plain kernel, graph-capture safe) ----
// bar layout (u32 idx): leaf i at i*32 (128B apart), root at 512, gen at 544.
// Monotonic counters, no resets, no ABA. Bounded spin -> fast-fail not hang.
__device__ __forceinline__ void grid_barrier(unsigned* bar, unsigned k, int blk)
{
    __syncthreads();
    if (threadIdx.x == 0) {
        __threadfence();   // release: writeback to device scope
        unsigned* leaf = bar + (blk & (NLEAF-1u))*32u;
        unsigned* root = bar + 512u;
        unsigned* gen  = bar + 544u;
        unsigned la = __hip_atomic_fetch_add(leaf, 1u, __ATOMIC_ACQ_REL, __HIP_MEMORY_SCOPE_AGENT);
        if (la == k*BPL + (BPL - 1u)) {
            unsigned ra = __hip_atomic_fetch_add(root, 1u, __ATOMIC_ACQ_REL, __HIP_MEMORY_SCOPE_AGENT);
            if (ra == k*NLEAF + (NLEAF - 1u)) {
                __hip_atomic_store(gen, k + 1u, __ATOMIC_RELEASE, __HIP_MEMORY_SCOPE_AGENT);
            }
        }
        int spin = 0;
        while (__hip_atomic_load(gen, __ATOMIC_RELAXED, __HIP_MEMORY_SCOPE_AGENT) < k + 1u
               && spin < 300000) {
            __builtin_amdgcn_s_sleep(2);
            ++spin;
        }
        __threadfence();   // acquire: invalidate stale cached lines
    }
    __syncthreads();
}

// ---------------- setup kernels ----------------

__global__ __launch_bounds__(256) void k_prep_weights(
    const float* __restrict__ W1, const float* __restrict__ Whh_f,
    const float* __restrict__ b_ih, const float* __restrict__ b_hh,
    __bf16* __restrict__ Wdc, __bf16* __restrict__ W1x, __bf16* __restrict__ Whh,
    float* __restrict__ bsum)
{
    int i = blockIdx.x*256 + threadIdx.x;
    int n = gridDim.x*256;
    for (int idx = i; idx < 512*1024; idx += n) {
        int f = idx >> 10, k = idx & 1023;
        Wdc[idx] = (__bf16)W1[f*1536 + k];
    }
    for (int idx = i; idx < 512*512; idx += n) {
        int f = idx >> 9, k = idx & 511;
        W1x[idx] = (__bf16)W1[f*1536 + 1024 + k];
    }
    for (int idx = i; idx < 2048*512; idx += n) {
        Whh[idx] = (__bf16)Whh_f[idx];
    }
    for (int idx = i; idx < 2048; idx += n) {
        bsum[idx] = b_ih[idx] + b_hh[idx];
    }
}

__global__ __launch_bounds__(256) void k_conv_x(const float* __restrict__ X, __bf16* __restrict__ Xb, int n)
{
    int idx = (blockIdx.x*256 + threadIdx.x)*4;
    if (idx < n) {
        float4 v = *(const float4*)(X + idx);
        Xb[idx+0] = (__bf16)v.x; Xb[idx+1] = (__bf16)v.y;
        Xb[idx+2] = (__bf16)v.z; Xb[idx+3] = (__bf16)v.w;
    }
}

// XF[m] = sum_e Xbf[m,e]*fcW[e]
__global__ __launch_bounds__(256) void k_xf(
    const __bf16* __restrict__ Xbf, const float* __restrict__ fcW, float* __restrict__ XF)
{
    int lane = threadIdx.x & 63, wave = threadIdx.x >> 6;
    float fcr[8];
    {
        const float4* fp = (const float4*)(fcW + lane*8);
        float4 f0 = fp[0], f1 = fp[1];
        fcr[0]=f0.x; fcr[1]=f0.y; fcr[2]=f0.z; fcr[3]=f0.w;
        fcr[4]=f1.x; fcr[5]=f1.y; fcr[6]=f1.z; fcr[7]=f1.w;
    }
    int row0 = (blockIdx.x*4 + wave)*8;
    #pragma unroll
    for (int j = 0; j < 8; ++j) {
        int row = row0 + j;
        if (row >= Bn*TM1) break;
        bf16x8 x = *(const bf16x8*)(Xbf + (size_t)row*512 + lane*8);
        float p = 0.f;
        #pragma unroll
        for (int i=0;i<8;i++) p += fcr[i]*(float)x[i];
        #pragma unroll
        for (int o=32;o;o>>=1) p += __shfl_xor(p,o,64);
        if (lane==0) XF[row] = p;
    }
}

// ---------------- LDS-staged 64x64-tile GEMM body (XOR-swizzled) ----------------
template <int ADDBIAS>
__device__ __forceinline__ void gemm_tile_lds(
    const __bf16* __restrict__ A, const __bf16* __restrict__ Bm,
    const float* __restrict__ bias, void* __restrict__ C, int as_bf16,
    int row0, int col0, int K, int lda, int ldb, int ldc,
    __bf16* sA, __bf16* sB)
{
    int lane = threadIdx.x & 63, wave = threadIdx.x >> 6;
    int wr = wave >> 1, wc = wave & 1;
    int l15 = lane & 15, l4 = lane >> 4;
    int lr = lane >> 3;
    int lcs = ((lane & 7) ^ lr) * 8;

    auto stage = [&](int buf, int kt) {
        int k0 = kt*64;
        #pragma unroll
        for (int j = 0; j < 2; ++j) {
            int c = wave*2 + j;
            int grow = c*8 + lr;
            gll16(A  + (size_t)(row0+grow)*lda + k0 + lcs, sA + buf*4096 + c*512);
            gll16(Bm + (size_t)(col0+grow)*ldb + k0 + lcs, sB + buf*4096 + c*512);
        }
    };

    int NT = K >> 6;
    stage(0, 0);
    f32x4 acc[2][2] = {};
    int s7 = l15 & 7;
    const __bf16* aRow = sA + (wr*32 + l15)*64;
    const __bf16* bRow = sB + (wc*32 + l15)*64;
    for (int kt = 0; kt < NT; ++kt) {
        int buf = kt & 1;
        asm volatile("s_waitcnt vmcnt(0)");
        __syncthreads();
        if (kt + 1 < NT) stage(buf ^ 1, kt + 1);
        #pragma unroll
        for (int kk = 0; kk < 2; ++kk) {
            int ch = ((l4 + kk*4) ^ s7) * 8;
            bf16x8 a0 = *(const bf16x8*)(aRow + buf*4096 + ch);
            bf16x8 a1 = *(const bf16x8*)(aRow + buf*4096 + 16*64 + ch);
            bf16x8 b0 = *(const bf16x8*)(bRow + buf*4096 + ch);
            bf16x8 b1 = *(const bf16x8*)(bRow + buf*4096 + 16*64 + ch);
            acc[0][0] = __builtin_amdgcn_mfma_f32_16x16x32_bf16(a0,b0,acc[0][0],0,0,0);
            acc[0][1] = __builtin_amdgcn_mfma_f32_16x16x32_bf16(a0,b1,acc[0][1],0,0,0);
            acc[1][0] = __builtin_amdgcn_mfma_f32_16x16x32_bf16(a1,b0,acc[1][0],0,0,0);
            acc[1][1] = __builtin_amdgcn_mfma_f32_16x16x32_bf16(a1,b1,acc[1][1],0,0,0);
        }
    }
    int row_a = row0 + wr*32;
    int col_b = col0 + wc*32;
    #pragma unroll
    for (int mi=0; mi<2; mi++)
    #pragma unroll
    for (int ni=0; ni<2; ni++) {
        int r0 = row_a + mi*16 + l4*4;
        int c0 = col_b + ni*16 + l15;
        float bv = ADDBIAS ? bias[c0] : 0.f;
        if (as_bf16) {
            __bf16* Cb = (__bf16*)C;
            #pragma unroll
            for (int r=0; r<4; r++)
                Cb[(size_t)(r0+r)*ldc + c0] = (__bf16)(acc[mi][ni][r] + bv);
        } else {
            float* Cf = (float*)C;
            #pragma unroll
            for (int r=0; r<4; r++)
                Cf[(size_t)(r0+r)*ldc + c0] = acc[mi][ni][r];
        }
    }
}

// XW[m,f] = sum_e Xbf[m,e]*W1x[f,e] + b1[f]
__global__ __launch_bounds__(256) void k_gemm_xw(
    const __bf16* __restrict__ A, const __bf16* __restrict__ Bm,
    const float* __restrict__ bias, __bf16* __restrict__ C)
{
    __shared__ __bf16 sA[2*4096], sB[2*4096];
    int orig = (blockIdx.x & 7)*504 + (blockIdx.x >> 3);
    int tm = orig >> 3, tn = orig & 7;
    gemm_tile_lds<1>(A, Bm, bias, C, 1, tm*64, tn*64, 512, 512, 512, 512, sA, sB);
}

// ---------------- per-step phase bodies ----------------

// Phase A: 384 jobs. 0..127: dcW K-halves -> dcWparts[kh][512][512];
// 128..383: dWhh [512x2048]. Blocks 384+ idle.
__device__ __forceinline__ void step_gemm_jobs(
    int blk, const __bf16* dcb, const __bf16* Wdc, const __bf16* Whh,
    float* dcWparts, float* dWhh_, __bf16* sA, __bf16* sB)
{
    if (blk < 128) {
        int kh = blk & 1, tt_ = blk >> 1, tm = tt_ >> 3, tn = tt_ & 7;
        gemm_tile_lds<0>(dcb + kh*512, Wdc + kh*512, nullptr,
                         dcWparts + (size_t)kh*512*512, 0,
                         tm*64, tn*64, 512, 1024, 1024, 512, sA, sB);
    } else if (blk < 384) {
        int b2 = blk - 128, tm = b2 >> 5, tn = b2 & 31;
        gemm_tile_lds<0>(dcb, Whh, nullptr, dWhh_, 0,
                         tm*64, tn*64, 512, 1024, 512, 2048, sA, sB);
    }
}

// Phase B: one batch row, 256 threads
__device__ __forceinline__ void fused_body(
    int b, int t,
    const float* dcWparts, const float* dWhh_,
    const __bf16* XWb, const float* XF, const float* y_prev,
    const float* W2, const float* fcW, const float* fcb,
    const float* W_ih, const float* bsum,
    float* cf, float* df, __bf16* dcb, float* b62,
    float* s_part, float* s_sc, float* s_y)
{
    int tid = threadIdx.x, lane = tid & 63, wave = tid >> 6;
    float w2r[8], dr[8];
    {
        const float4* w2p = (const float4*)(W2 + lane*8);
        const float4* d0p = (const float4*)(dcWparts + (size_t)b*512 + lane*8);
        const float4* d1p = (const float4*)(dcWparts + (size_t)512*512 + (size_t)b*512 + lane*8);
        float4 w0 = w2p[0], w1 = w2p[1];
        float4 a0 = d0p[0], a1 = d0p[1], c0 = d1p[0], c1 = d1p[1];
        w2r[0]=w0.x; w2r[1]=w0.y; w2r[2]=w0.z; w2r[3]=w0.w;
        w2r[4]=w1.x; w2r[5]=w1.y; w2r[6]=w1.z; w2r[7]=w1.w;
        dr[0]=a0.x+c0.x; dr[1]=a0.y+c0.y; dr[2]=a0.z+c0.z; dr[3]=a0.w+c0.w;
        dr[4]=a1.x+c1.x; dr[5]=a1.y+c1.y; dr[6]=a1.z+c1.z; dr[7]=a1.w+c1.w;
    }
    // scores: wave w -> t in {w*16..w*16+15}, lane = f-slice
    {
        const __bf16* xwp = XWb + ((size_t)b*TM1 + wave*16)*512 + lane*8;
        #pragma unroll
        for (int j = 0; j < 16; ++j) {
            int tt = wave*16 + j;
            float p = 0.f;
            if (tt < TM1) {
                bf16x8 xw = *(const bf16x8*)(xwp + (size_t)j*512);
                #pragma unroll
                for (int i=0;i<8;i++) p += w2r[i]*fast_tanh(dr[i] + (float)xw[i]);
            }
            s_part[tt*PSTR + lane] = p;
        }
    }
    __syncthreads();
    // reduce: tt = tid>>2 (0..63), g = tid&3 (16 floats each)
    {
        int tt = tid >> 2, g = tid & 3;
        const float4* pp = (const float4*)(s_part + tt*PSTR + g*16);
        float4 u0 = pp[0], u1 = pp[1], u2 = pp[2], u3 = pp[3];
        float r = u0.x+u0.y+u0.z+u0.w + u1.x+u1.y+u1.z+u1.w
                + u2.x+u2.y+u2.z+u2.w + u3.x+u3.y+u3.z+u3.w;
        r += __shfl_xor(r, 1, 64);
        r += __shfl_xor(r, 2, 64);
        if (g == 0) s_sc[tt] = r;
    }
    __syncthreads();
    // softmax + y (wave 0); no max pass (|s| <= sum|W2| ~ 19)
    if (wave == 0) {
        float e = (lane < TM1) ? __expf(s_sc[lane]) : 0.f;
        float sum = e;
        #pragma unroll
        for (int o=32;o;o>>=1) sum += __shfl_xor(sum,o,64);
        float beta = e*fast_rcp(sum);
        if (t == 62) b62[b*64 + lane] = beta;
        float yp = (lane < TM1) ? beta*XF[(size_t)b*TM1 + lane] : 0.f;
        #pragma unroll
        for (int o=32;o;o>>=1) yp += __shfl_xor(yp,o,64);
        if (lane == 0)
            *s_y = yp + fcW[512]*y_prev[(size_t)b*TM1 + t] + fcb[0];
    }
    __syncthreads();
    float yv = *s_y;
    // gates + state update: 2 k's per thread
    #pragma unroll
    for (int r2 = 0; r2 < 2; ++r2) {
        int k = tid + r2*256;
        size_t gb = (size_t)b*2048 + k;
        float gi = dWhh_[gb]        + yv*W_ih[k]        + bsum[k];
        float gf = dWhh_[gb+512]    + yv*W_ih[512+k]    + bsum[512+k];
        float gg = dWhh_[gb+1024]   + yv*W_ih[1024+k]   + bsum[1024+k];
        float go = dWhh_[gb+1536]   + yv*W_ih[1536+k]   + bsum[1536+k];
        size_t sk = (size_t)b*512 + k;
        float cn = fast_sigmoid(gf)*cf[sk] + fast_sigmoid(gi)*fast_tanh(gg);
        float dn = fast_sigmoid(go)*fast_tanh(cn);
        cf[sk] = cn; df[sk] = dn;
        dcb[(size_t)b*1024 + k]       = (__bf16)dn;
        dcb[(size_t)b*1024 + 512 + k] = (__bf16)cn;
    }
}

// ---------------- persistent kernel ----------------
// LDS: phase A (sA/sB, 32KB) UNIONed with phase B (s_part/s_sc/s_y, ~19.7KB)
// -> 32KB/block -> 5 blocks/CU by LDS; __launch_bounds__(256,4) caps VGPR at 128
// -> 4 blocks/CU -> capacity 1024 >= 2x NBLK(512). No exact-fit deadlock.

struct PParams {
    const __bf16 *Wdc, *Whh, *XWb;
    const float *XF, *y_prev, *W2, *fcW, *fcb, *W_ih, *bsum;
    float *dcWparts, *dWhh_, *cf, *df, *b62;
    __bf16 *dcb;
    unsigned *bar;
};

__global__ __launch_bounds__(256, 4) void k_persist(PParams p)
{
    __shared__ char smem[32768] __attribute__((aligned(16)));
    __bf16* sA     = (__bf16*)smem;                    // phase A: [0, 16KB)
    __bf16* sB     = (__bf16*)(smem + 16384);          // phase A: [16KB, 32KB)
    float*  s_part = (float*)smem;                     // phase B: [0, 19456)
    float*  s_sc   = (float*)(smem + 19456);           // phase B: 256B
    float*  s_y    = (float*)(smem + 19712);           // phase B: 4B
    int blk = blockIdx.x;
    unsigned bk = 0;

    for (int t = 0; t < TM1; ++t) {
        step_gemm_jobs(blk, p.dcb, p.Wdc, p.Whh, p.dcWparts, p.dWhh_, sA, sB);
        grid_barrier(p.bar, bk++, blk);
        fused_body(blk, t, p.dcWparts, p.dWhh_, p.XWb, p.XF, p.y_prev,
                   p.W2, p.fcW, p.fcb, p.W_ih, p.bsum,
                   p.cf, p.df, p.dcb, p.b62, s_part, s_sc, s_y);
        grid_barrier(p.bar, bk++, blk);
    }
}

// ---------------- finish: ctx_last from beta(62) + heads ----------------
__global__ __launch_bounds__(512) void k_finish(
    const float* __restrict__ beta62, const __bf16* __restrict__ Xbf,
    const float* __restrict__ d_f32,
    const float* __restrict__ bW, const float* __restrict__ bb,
    const float* __restrict__ sW, const float* __restrict__ sb,
    const float* __restrict__ gW, const float* __restrict__ gb,
    float* __restrict__ out)
{
    int b = blockIdx.x;
    int tid = threadIdx.x, lane = tid & 63, wave = tid >> 6;
    __shared__ float s_beta[64];
    __shared__ float s_red[3][8];
    if (tid < 64) s_beta[tid] = beta62[b*64 + tid];
    __syncthreads();
    float ctxv = 0.f;
    {
        const __bf16* xp = Xbf + (size_t)b*TM1*512 + tid;
        #pragma unroll
        for (int tt = 0; tt < TM1; ++tt)
            ctxv += s_beta[tt]*(float)xp[(size_t)tt*512];
    }
    float dv = d_f32[(size_t)b*512 + tid];
    float pb = bW[tid]*dv + bW[512+tid]*ctxv;
    float ps = sW[tid]*dv + sW[512+tid]*ctxv;
    float pg = gW[tid]*dv + gW[512+tid]*ctxv;
    #pragma unroll
    for (int o=32;o;o>>=1) {
        pb += __shfl_xor(pb,o,64); ps += __shfl_xor(ps,o,64); pg += __shfl_xor(pg,o,64);
    }
    if (lane==0) { s_red[0][wave]=pb; s_red[1][wave]=ps; s_red[2][wave]=pg; }
    __syncthreads();
    if (tid==0) {
        float sb_=0,ss_=0,sg_=0;
        #pragma unroll
        for (int w=0;w<8;w++){ sb_+=s_red[0][w]; ss_+=s_red[1][w]; sg_+=s_red[2][w]; }
        out[b]        = sb_ + bb[0];
        out[512 + b]  = ss_ + sb[0];
        out[1024 + b] = sg_ + gb[0];
    }
}

extern "C" void kernel_launch(void* const* d_in, const int* in_sizes, int n_in,
                              void* d_out, int out_size, void* d_ws, size_t ws_size,
                              hipStream_t stream) {
    const float* X      = (const float*)d_in[0];
    const float* y_prev = (const float*)d_in[1];
    const float* W1     = (const float*)d_in[2];
    const float* b1     = (const float*)d_in[3];
    const float* W2     = (const float*)d_in[4];
    // d_in[5] = attn_b2 (softmax-invariant constant shift, skipped)
    const float* fcW    = (const float*)d_in[6];
    const float* fcb    = (const float*)d_in[7];
    const float* W_ih   = (const float*)d_in[8];
    const float* W_hh_f = (const float*)d_in[9];
    const float* b_ih   = (const float*)d_in[10];
    const float* b_hh   = (const float*)d_in[11];
    const float* betaW  = (const float*)d_in[12];
    const float* betab  = (const float*)d_in[13];
    const float* gammaW = (const float*)d_in[14];
    const float* gammab = (const float*)d_in[15];
    const float* sigmaW = (const float*)d_in[16];
    const float* sigmab = (const float*)d_in[17];
    float* out = (float*)d_out;

    size_t off = 0;
    char* ws = (char*)d_ws;
    auto alloc = [&](size_t bytes) { void* p = ws + off; off += (bytes + 255) & ~(size_t)255; return p; };
    __bf16* XWb  = (__bf16*)alloc((size_t)Bn*TM1*512*2);
    __bf16* Xbf  = (__bf16*)alloc((size_t)Bn*TM1*512*2);
    __bf16* Wdc  = (__bf16*)alloc((size_t)512*1024*2);
    __bf16* W1x  = (__bf16*)alloc((size_t)512*512*2);
    __bf16* Whh  = (__bf16*)alloc((size_t)2048*512*2);
    __bf16* dcb  = (__bf16*)alloc((size_t)Bn*1024*2);
    float*  cf   = (float*)alloc((size_t)Bn*512*4);
    float*  df   = (float*)alloc((size_t)Bn*512*4);
    float*  dcWp = (float*)alloc((size_t)2*512*512*4);
    float*  dWhh = (float*)alloc((size_t)Bn*2048*4);
    float*  bsum = (float*)alloc((size_t)2048*4);
    float*  XF   = (float*)alloc((size_t)Bn*TM1*4);
    float*  b62  = (float*)alloc((size_t)Bn*64*4);
    unsigned* bar = (unsigned*)alloc(4096);

    hipMemsetAsync(dcb, 0, (size_t)Bn*1024*2, stream);
    hipMemsetAsync(cf,  0, (size_t)Bn*512*4, stream);
    hipMemsetAsync(bar, 0, 4096, stream);

    k_prep_weights<<<512, 256, 0, stream>>>(W1, W_hh_f, b_ih, b_hh, Wdc, W1x, Whh, bsum);
    int nx = Bn*TM1*512;
    k_conv_x<<<(nx/4 + 255)/256, 256, 0, stream>>>(X, Xbf, nx);
    k_xf<<<(Bn*TM1 + 31)/32, 256, 0, stream>>>(Xbf, fcW, XF);
    k_gemm_xw<<<(Bn*TM1/64)*8, 256, 0, stream>>>(Xbf, W1x, b1, XWb);

    PParams pp;
    pp.Wdc = Wdc; pp.Whh = Whh; pp.XWb = XWb;
    pp.XF = XF; pp.y_prev = y_prev; pp.W2 = W2; pp.fcW = fcW; pp.fcb = fcb;
    pp.W_ih = W_ih; pp.bsum = bsum;
    pp.dcWparts = dcWp; pp.dWhh_ = dWhh; pp.cf = cf; pp.df = df; pp.b62 = b62;
    pp.dcb = dcb; pp.bar = bar;
    k_persist<<<NBLK, 256, 0, stream>>>(pp);

    k_finish<<<Bn, 512, 0, stream>>>(b62, Xbf, df,
                                     betaW, betab, sigmaW, sigmab, gammaW, gammab, out);
}

// Round 10
// 1983.120 us; speedup vs baseline: 3.2861x; 3.2861x over previous
//
#include <hip/hip_runtime.h>

typedef __bf16 bf16x8 __attribute__((ext_vector_type(8)));
typedef float  f32x4  __attribute__((ext_vector_type(4)));

#define Bn  512
#define TM1 63
#define PSTR 76
#define NBLK 512u
#define NLEAF 16u
#define BPL 32u
#define SLOT (512*1024)   // dcb ring slot (bf16 elems) = 1MB

__device__ __forceinline__ float fast_rcp(float x){ return __builtin_amdgcn_rcpf(x); }
__device__ __forceinline__ float fast_tanh(float x){
    float e = __expf(2.0f*x);
    return 1.0f - 2.0f*fast_rcp(e + 1.0f);
}
__device__ __forceinline__ float fast_sigmoid(float x){
    return fast_rcp(1.0f + __expf(-x));
}

// async global->LDS, 16B per lane; lds ptr must be wave-uniform (HW adds lane*16)
__device__ __forceinline__ void gll16(const __bf16* g, __bf16* l) {
    __builtin_amdgcn_global_load_lds(
        (const __attribute__((address_space(1))) unsigned int*)(g),
        (__attribute__((address_space(3))) unsigned int*)(l),
        16, 0, 0);
}

// device-coherent (agent) write-through store: visible in L3 after vmcnt drain
__device__ __forceinline__ void st_f32_sc(float* p, float v) {
    asm volatile("global_store_dword %0, %1, off sc0 sc1" :: "v"(p), "v"(v) : "memory");
}

// ---- relaxed two-level grid barrier: NO fences, NO cache invalidation ----
// Monotonic counters (no ABA). Release = vmcnt drain of sc1 stores before arrive.
__device__ __forceinline__ void grid_barrier(unsigned* bar, unsigned k, int blk)
{
    __syncthreads();
    if (threadIdx.x == 0) {
        asm volatile("s_waitcnt vmcnt(0) lgkmcnt(0)" ::: "memory");
        unsigned* leaf = bar + (blk & (NLEAF-1u))*32u;
        unsigned* root = bar + 512u;
        unsigned* gen  = bar + 544u;
        unsigned la = __hip_atomic_fetch_add(leaf, 1u, __ATOMIC_RELAXED, __HIP_MEMORY_SCOPE_AGENT);
        if (la == k*BPL + (BPL - 1u)) {
            unsigned ra = __hip_atomic_fetch_add(root, 1u, __ATOMIC_RELAXED, __HIP_MEMORY_SCOPE_AGENT);
            if (ra == k*NLEAF + (NLEAF - 1u))
                __hip_atomic_store(gen, k + 1u, __ATOMIC_RELAXED, __HIP_MEMORY_SCOPE_AGENT);
        }
        int spin = 0;
        while (__hip_atomic_load(gen, __ATOMIC_RELAXED, __HIP_MEMORY_SCOPE_AGENT) < k + 1u
               && spin < 1000000) {
            __builtin_amdgcn_s_sleep(2);
            ++spin;
        }
    }
    __syncthreads();
}

// ---------------- setup kernels ----------------

__global__ __launch_bounds__(256) void k_prep_weights(
    const float* __restrict__ W1, const float* __restrict__ Whh_f,
    const float* __restrict__ b_ih, const float* __restrict__ b_hh,
    __bf16* __restrict__ Wdc, __bf16* __restrict__ W1x, __bf16* __restrict__ Whh,
    float* __restrict__ bsum)
{
    int i = blockIdx.x*256 + threadIdx.x;
    int n = gridDim.x*256;
    for (int idx = i; idx < 512*1024; idx += n) {
        int f = idx >> 10, k = idx & 1023;
        Wdc[idx] = (__bf16)W1[f*1536 + k];
    }
    for (int idx = i; idx < 512*512; idx += n) {
        int f = idx >> 9, k = idx & 511;
        W1x[idx] = (__bf16)W1[f*1536 + 1024 + k];
    }
    for (int idx = i; idx < 2048*512; idx += n) {
        Whh[idx] = (__bf16)Whh_f[idx];
    }
    for (int idx = i; idx < 2048; idx += n) {
        bsum[idx] = b_ih[idx] + b_hh[idx];
    }
}

__global__ __launch_bounds__(256) void k_conv_x(const float* __restrict__ X, __bf16* __restrict__ Xb, int n)
{
    int idx = (blockIdx.x*256 + threadIdx.x)*4;
    if (idx < n) {
        float4 v = *(const float4*)(X + idx);
        Xb[idx+0] = (__bf16)v.x; Xb[idx+1] = (__bf16)v.y;
        Xb[idx+2] = (__bf16)v.z; Xb[idx+3] = (__bf16)v.w;
    }
}

// XF[m] = sum_e Xbf[m,e]*fcW[e]
__global__ __launch_bounds__(256) void k_xf(
    const __bf16* __restrict__ Xbf, const float* __restrict__ fcW, float* __restrict__ XF)
{
    int lane = threadIdx.x & 63, wave = threadIdx.x >> 6;
    float fcr[8];
    {
        const float4* fp = (const float4*)(fcW + lane*8);
        float4 f0 = fp[0], f1 = fp[1];
        fcr[0]=f0.x; fcr[1]=f0.y; fcr[2]=f0.z; fcr[3]=f0.w;
        fcr[4]=f1.x; fcr[5]=f1.y; fcr[6]=f1.z; fcr[7]=f1.w;
    }
    int row0 = (blockIdx.x*4 + wave)*8;
    #pragma unroll
    for (int j = 0; j < 8; ++j) {
        int row = row0 + j;
        if (row >= Bn*TM1) break;
        bf16x8 x = *(const bf16x8*)(Xbf + (size_t)row*512 + lane*8);
        float p = 0.f;
        #pragma unroll
        for (int i=0;i<8;i++) p += fcr[i]*(float)x[i];
        #pragma unroll
        for (int o=32;o;o>>=1) p += __shfl_xor(p,o,64);
        if (lane==0) XF[row] = p;
    }
}

// ---------------- LDS-staged 64x64-tile GEMM body (XOR-swizzled) ----------------
// SC1ST: float C-writes go device-coherent (write-through to L3)
template <int ADDBIAS, int SC1ST>
__device__ __forceinline__ void gemm_tile_lds(
    const __bf16* __restrict__ A, const __bf16* __restrict__ Bm,
    const float* __restrict__ bias, void* __restrict__ C, int as_bf16,
    int row0, int col0, int K, int lda, int ldb, int ldc,
    __bf16* sA, __bf16* sB)
{
    int lane = threadIdx.x & 63, wave = threadIdx.x >> 6;
    int wr = wave >> 1, wc = wave & 1;
    int l15 = lane & 15, l4 = lane >> 4;
    int lr = lane >> 3;
    int lcs = ((lane & 7) ^ lr) * 8;

    auto stage = [&](int buf, int kt) {
        int k0 = kt*64;
        #pragma unroll
        for (int j = 0; j < 2; ++j) {
            int c = wave*2 + j;
            int grow = c*8 + lr;
            gll16(A  + (size_t)(row0+grow)*lda + k0 + lcs, sA + buf*4096 + c*512);
            gll16(Bm + (size_t)(col0+grow)*ldb + k0 + lcs, sB + buf*4096 + c*512);
        }
    };

    int NT = K >> 6;
    stage(0, 0);
    f32x4 acc[2][2] = {};
    int s7 = l15 & 7;
    const __bf16* aRow = sA + (wr*32 + l15)*64;
    const __bf16* bRow = sB + (wc*32 + l15)*64;
    for (int kt = 0; kt < NT; ++kt) {
        int buf = kt & 1;
        asm volatile("s_waitcnt vmcnt(0)");
        __syncthreads();
        if (kt + 1 < NT) stage(buf ^ 1, kt + 1);
        #pragma unroll
        for (int kk = 0; kk < 2; ++kk) {
            int ch = ((l4 + kk*4) ^ s7) * 8;
            bf16x8 a0 = *(const bf16x8*)(aRow + buf*4096 + ch);
            bf16x8 a1 = *(const bf16x8*)(aRow + buf*4096 + 16*64 + ch);
            bf16x8 b0 = *(const bf16x8*)(bRow + buf*4096 + ch);
            bf16x8 b1 = *(const bf16x8*)(bRow + buf*4096 + 16*64 + ch);
            acc[0][0] = __builtin_amdgcn_mfma_f32_16x16x32_bf16(a0,b0,acc[0][0],0,0,0);
            acc[0][1] = __builtin_amdgcn_mfma_f32_16x16x32_bf16(a0,b1,acc[0][1],0,0,0);
            acc[1][0] = __builtin_amdgcn_mfma_f32_16x16x32_bf16(a1,b0,acc[1][0],0,0,0);
            acc[1][1] = __builtin_amdgcn_mfma_f32_16x16x32_bf16(a1,b1,acc[1][1],0,0,0);
        }
    }
    int row_a = row0 + wr*32;
    int col_b = col0 + wc*32;
    #pragma unroll
    for (int mi=0; mi<2; mi++)
    #pragma unroll
    for (int ni=0; ni<2; ni++) {
        int r0 = row_a + mi*16 + l4*4;
        int c0 = col_b + ni*16 + l15;
        float bv = ADDBIAS ? bias[c0] : 0.f;
        if (as_bf16) {
            __bf16* Cb = (__bf16*)C;
            #pragma unroll
            for (int r=0; r<4; r++)
                Cb[(size_t)(r0+r)*ldc + c0] = (__bf16)(acc[mi][ni][r] + bv);
        } else {
            float* Cf = (float*)C;
            #pragma unroll
            for (int r=0; r<4; r++) {
                if (SC1ST) st_f32_sc(&Cf[(size_t)(r0+r)*ldc + c0], acc[mi][ni][r]);
                else       Cf[(size_t)(r0+r)*ldc + c0] = acc[mi][ni][r];
            }
        }
    }
}

// XW[m,f] = sum_e Xbf[m,e]*W1x[f,e] + b1[f]
__global__ __launch_bounds__(256) void k_gemm_xw(
    const __bf16* __restrict__ A, const __bf16* __restrict__ Bm,
    const float* __restrict__ bias, __bf16* __restrict__ C)
{
    __shared__ __bf16 sA[2*4096], sB[2*4096];
    int orig = (blockIdx.x & 7)*504 + (blockIdx.x >> 3);
    int tm = orig >> 3, tn = orig & 7;
    gemm_tile_lds<1,0>(A, Bm, bias, C, 1, tm*64, tn*64, 512, 512, 512, 512, sA, sB);
}

// ---------------- per-step phase bodies ----------------

// Phase A: 384 jobs. 0..127: dcW K-halves -> dcWp[kh][512][512]; 128..383: dWhh.
__device__ __forceinline__ void step_gemm_jobs(
    int blk, const __bf16* dcb_rd, const __bf16* Wdc, const __bf16* Whh,
    float* dcWp, float* dWhh_, __bf16* sA, __bf16* sB)
{
    if (blk < 128) {
        int kh = blk & 1, tt_ = blk >> 1, tm = tt_ >> 3, tn = tt_ & 7;
        gemm_tile_lds<0,1>(dcb_rd + kh*512, Wdc + kh*512, nullptr,
                           dcWp + (size_t)kh*512*512, 0,
                           tm*64, tn*64, 512, 1024, 1024, 512, sA, sB);
    } else if (blk < 384) {
        int b2 = blk - 128, tm = b2 >> 5, tn = b2 & 31;
        gemm_tile_lds<0,1>(dcb_rd, Whh, nullptr, dWhh_, 0,
                           tm*64, tn*64, 512, 1024, 512, 2048, sA, sB);
    }
}

// Phase B: one batch row, 256 threads. Cross-XCD inputs (dcWp, dWhh_) via sc1 loads;
// dcb written to ring slot via sc1 (write-through) stores.
__device__ __forceinline__ void fused_body(
    int b, int t,
    const float* dcWp, const float* dWhh_,
    const __bf16* XWb, const float* XF, const float* y_prev,
    const float* W2, const float* fcW, const float* fcb,
    const float* W_ih, const float* bsum,
    float* cf, float* df, __bf16* dcb_wr, float* b62,
    float* s_part, float* s_sc, float* s_y)
{
    int tid = threadIdx.x, lane = tid & 63, wave = tid >> 6;

    // batched coherent loads: dcW row slices (2 K-halves) + 8 gate pre-activations
    const float* p0 = dcWp + (size_t)b*512 + lane*8;
    const float* p1 = p0 + (size_t)512*512;
    const float* g0 = dWhh_ + (size_t)b*2048 + tid;
    const float* g1 = g0 + 1024;
    f32x4 da0, da1, dc0, dc1;
    float gi0,gf0,gg0,go0,gi1,gf1,gg1,go1;
    asm volatile(
        "global_load_dwordx4 %0, %12, off sc0 sc1\n\t"
        "global_load_dwordx4 %1, %12, off offset:16 sc0 sc1\n\t"
        "global_load_dwordx4 %2, %13, off sc0 sc1\n\t"
        "global_load_dwordx4 %3, %13, off offset:16 sc0 sc1\n\t"
        "global_load_dword %4, %14, off sc0 sc1\n\t"
        "global_load_dword %5, %14, off offset:2048 sc0 sc1\n\t"
        "global_load_dword %6, %15, off sc0 sc1\n\t"
        "global_load_dword %7, %15, off offset:2048 sc0 sc1\n\t"
        "global_load_dword %8, %14, off offset:1024 sc0 sc1\n\t"
        "global_load_dword %9, %14, off offset:3072 sc0 sc1\n\t"
        "global_load_dword %10, %15, off offset:1024 sc0 sc1\n\t"
        "global_load_dword %11, %15, off offset:3072 sc0 sc1\n\t"
        "s_waitcnt vmcnt(0)"
        : "=&v"(da0), "=&v"(da1), "=&v"(dc0), "=&v"(dc1),
          "=&v"(gi0), "=&v"(gf0), "=&v"(gg0), "=&v"(go0),
          "=&v"(gi1), "=&v"(gf1), "=&v"(gg1), "=&v"(go1)
        : "v"(p0), "v"(p1), "v"(g0), "v"(g1)
        : "memory");

    float w2r[8], dr[8];
    {
        const float4* w2p = (const float4*)(W2 + lane*8);
        float4 w0 = w2p[0], w1 = w2p[1];
        w2r[0]=w0.x; w2r[1]=w0.y; w2r[2]=w0.z; w2r[3]=w0.w;
        w2r[4]=w1.x; w2r[5]=w1.y; w2r[6]=w1.z; w2r[7]=w1.w;
        #pragma unroll
        for (int i=0;i<4;i++) { dr[i] = da0[i]+dc0[i]; dr[4+i] = da1[i]+dc1[i]; }
    }
    // scores: wave w -> t in {w*16..w*16+15}, lane = f-slice (XWb normal/cached)
    {
        const __bf16* xwp = XWb + ((size_t)b*TM1 + wave*16)*512 + lane*8;
        #pragma unroll
        for (int j = 0; j < 16; ++j) {
            int tt = wave*16 + j;
            float p = 0.f;
            if (tt < TM1) {
                bf16x8 xw = *(const bf16x8*)(xwp + (size_t)j*512);
                #pragma unroll
                for (int i=0;i<8;i++) p += w2r[i]*fast_tanh(dr[i] + (float)xw[i]);
            }
            s_part[tt*PSTR + lane] = p;
        }
    }
    __syncthreads();
    {
        int tt = tid >> 2, g = tid & 3;
        const float4* pp = (const float4*)(s_part + tt*PSTR + g*16);
        float4 u0 = pp[0], u1 = pp[1], u2 = pp[2], u3 = pp[3];
        float r = u0.x+u0.y+u0.z+u0.w + u1.x+u1.y+u1.z+u1.w
                + u2.x+u2.y+u2.z+u2.w + u3.x+u3.y+u3.z+u3.w;
        r += __shfl_xor(r, 1, 64);
        r += __shfl_xor(r, 2, 64);
        if (g == 0) s_sc[tt] = r;
    }
    __syncthreads();
    if (wave == 0) {
        float e = (lane < TM1) ? __expf(s_sc[lane]) : 0.f;
        float sum = e;
        #pragma unroll
        for (int o=32;o;o>>=1) sum += __shfl_xor(sum,o,64);
        float beta = e*fast_rcp(sum);
        if (t == 62) b62[b*64 + lane] = beta;
        float yp = (lane < TM1) ? beta*XF[(size_t)b*TM1 + lane] : 0.f;
        #pragma unroll
        for (int o=32;o;o>>=1) yp += __shfl_xor(yp,o,64);
        if (lane == 0)
            *s_y = yp + fcW[512]*y_prev[(size_t)b*TM1 + t] + fcb[0];
    }
    __syncthreads();
    float yv = *s_y;
    // gates + state: k0 = tid, k1 = tid+256 (pre-activations already loaded)
    {
        int k0 = tid, k1 = tid + 256;
        size_t sk0 = (size_t)b*512 + k0, sk1 = (size_t)b*512 + k1;
        float i0 = gi0 + yv*W_ih[k0]      + bsum[k0];
        float f0 = gf0 + yv*W_ih[512+k0]  + bsum[512+k0];
        float gg0v = gg0 + yv*W_ih[1024+k0] + bsum[1024+k0];
        float o0 = go0 + yv*W_ih[1536+k0] + bsum[1536+k0];
        float i1 = gi1 + yv*W_ih[k1]      + bsum[k1];
        float f1 = gf1 + yv*W_ih[512+k1]  + bsum[512+k1];
        float gg1v = gg1 + yv*W_ih[1024+k1] + bsum[1024+k1];
        float o1 = go1 + yv*W_ih[1536+k1] + bsum[1536+k1];
        float cn0 = fast_sigmoid(f0)*cf[sk0] + fast_sigmoid(i0)*fast_tanh(gg0v);
        float cn1 = fast_sigmoid(f1)*cf[sk1] + fast_sigmoid(i1)*fast_tanh(gg1v);
        float dn0 = fast_sigmoid(o0)*fast_tanh(cn0);
        float dn1 = fast_sigmoid(o1)*fast_tanh(cn1);
        cf[sk0] = cn0; cf[sk1] = cn1;            // block-private, cached
        if (t == 62) { df[sk0] = dn0; df[sk1] = dn1; }
        __bf16 hdn0=(__bf16)dn0, hdn1=(__bf16)dn1, hcn0=(__bf16)cn0, hcn1=(__bf16)cn1;
        unsigned udn0=*(unsigned short*)&hdn0, udn1=*(unsigned short*)&hdn1;
        unsigned ucn0=*(unsigned short*)&hcn0, ucn1=*(unsigned short*)&hcn1;
        __bf16* base = dcb_wr + (size_t)b*1024 + tid;
        asm volatile(
            "global_store_short %0, %1, off sc0 sc1\n\t"
            "global_store_short %0, %2, off offset:512 sc0 sc1\n\t"
            "global_store_short %0, %3, off offset:1024 sc0 sc1\n\t"
            "global_store_short %0, %4, off offset:1536 sc0 sc1"
            :: "v"(base), "v"(udn0), "v"(udn1), "v"(ucn0), "v"(ucn1) : "memory");
    }
}

// ---------------- persistent kernel ----------------
// LDS union 32KB -> 5 blocks/CU by LDS; launch_bounds(256,4) -> 4 blocks/CU
// -> capacity 1024 >= 2x NBLK. Proven to run in R9.

struct PParams {
    const __bf16 *Wdc, *Whh, *XWb;
    const float *XF, *y_prev, *W2, *fcW, *fcb, *W_ih, *bsum;
    float *dcWp, *dWhh_, *cf, *df, *b62;
    __bf16 *dcbRing;
    unsigned *bar;
};

__global__ __launch_bounds__(256, 4) void k_persist(PParams p)
{
    __shared__ char smem[32768] __attribute__((aligned(16)));
    __bf16* sA     = (__bf16*)smem;
    __bf16* sB     = (__bf16*)(smem + 16384);
    float*  s_part = (float*)smem;
    float*  s_sc   = (float*)(smem + 19456);
    float*  s_y    = (float*)(smem + 19712);
    int blk = blockIdx.x;
    unsigned bk = 0;

    for (int t = 0; t < TM1; ++t) {
        const __bf16* dcb_rd = p.dcbRing + (size_t)t*SLOT;
        __bf16* dcb_wr = p.dcbRing + (size_t)(t+1)*SLOT;
        step_gemm_jobs(blk, dcb_rd, p.Wdc, p.Whh, p.dcWp, p.dWhh_, sA, sB);
        grid_barrier(p.bar, bk++, blk);
        fused_body(blk, t, p.dcWp, p.dWhh_, p.XWb, p.XF, p.y_prev,
                   p.W2, p.fcW, p.fcb, p.W_ih, p.bsum,
                   p.cf, p.df, p.dcbRing + (size_t)(t+1)*SLOT, p.b62, s_part, s_sc, s_y);
        grid_barrier(p.bar, bk++, blk);
        (void)dcb_wr;
    }
}

// ---------------- fallback discrete kernels (2-slot ring) ----------------

__global__ __launch_bounds__(256) void k_stepA(
    const __bf16* __restrict__ dcb_rd, const __bf16* __restrict__ Wdc,
    const __bf16* __restrict__ Whh, float* __restrict__ dcWp, float* __restrict__ dWhh_)
{
    __shared__ __bf16 sA[2*4096], sB[2*4096];
    step_gemm_jobs(blockIdx.x, dcb_rd, Wdc, Whh, dcWp, dWhh_, sA, sB);
}

__global__ __launch_bounds__(256) void k_stepB(
    int t, const float* __restrict__ dcWp, const float* __restrict__ dWhh_,
    const __bf16* __restrict__ XWb, const float* __restrict__ XF,
    const float* __restrict__ y_prev, const float* __restrict__ W2,
    const float* __restrict__ fcW, const float* __restrict__ fcb,
    const float* __restrict__ W_ih, const float* __restrict__ bsum,
    float* __restrict__ cf, float* __restrict__ df,
    __bf16* __restrict__ dcb_wr, float* __restrict__ b62)
{
    __shared__ float s_part[64*PSTR];
    __shared__ float s_sc[64];
    __shared__ float s_y;
    fused_body(blockIdx.x, t, dcWp, dWhh_, XWb, XF, y_prev, W2, fcW, fcb,
               W_ih, bsum, cf, df, dcb_wr, b62, s_part, s_sc, &s_y);
}

// ---------------- finish: ctx_last from beta(62) + heads ----------------
__global__ __launch_bounds__(512) void k_finish(
    const float* __restrict__ beta62, const __bf16* __restrict__ Xbf,
    const float* __restrict__ d_f32,
    const float* __restrict__ bW, const float* __restrict__ bb,
    const float* __restrict__ sW, const float* __restrict__ sb,
    const float* __restrict__ gW, const float* __restrict__ gb,
    float* __restrict__ out)
{
    int b = blockIdx.x;
    int tid = threadIdx.x, lane = tid & 63, wave = tid >> 6;
    __shared__ float s_beta[64];
    __shared__ float s_red[3][8];
    if (tid < 64) s_beta[tid] = beta62[b*64 + tid];
    __syncthreads();
    float ctxv = 0.f;
    {
        const __bf16* xp = Xbf + (size_t)b*TM1*512 + tid;
        #pragma unroll
        for (int tt = 0; tt < TM1; ++tt)
            ctxv += s_beta[tt]*(float)xp[(size_t)tt*512];
    }
    float dv = d_f32[(size_t)b*512 + tid];
    float pb = bW[tid]*dv + bW[512+tid]*ctxv;
    float ps = sW[tid]*dv + sW[512+tid]*ctxv;
    float pg = gW[tid]*dv + gW[512+tid]*ctxv;
    #pragma unroll
    for (int o=32;o;o>>=1) {
        pb += __shfl_xor(pb,o,64); ps += __shfl_xor(ps,o,64); pg += __shfl_xor(pg,o,64);
    }
    if (lane==0) { s_red[0][wave]=pb; s_red[1][wave]=ps; s_red[2][wave]=pg; }
    __syncthreads();
    if (tid==0) {
        float sb_=0,ss_=0,sg_=0;
        #pragma unroll
        for (int w=0;w<8;w++){ sb_+=s_red[0][w]; ss_+=s_red[1][w]; sg_+=s_red[2][w]; }
        out[b]        = sb_ + bb[0];
        out[512 + b]  = ss_ + sb[0];
        out[1024 + b] = sg_ + gb[0];
    }
}

extern "C" void kernel_launch(void* const* d_in, const int* in_sizes, int n_in,
                              void* d_out, int out_size, void* d_ws, size_t ws_size,
                              hipStream_t stream) {
    const float* X      = (const float*)d_in[0];
    const float* y_prev = (const float*)d_in[1];
    const float* W1     = (const float*)d_in[2];
    const float* b1     = (const float*)d_in[3];
    const float* W2     = (const float*)d_in[4];
    // d_in[5] = attn_b2 (softmax-invariant constant shift, skipped)
    const float* fcW    = (const float*)d_in[6];
    const float* fcb    = (const float*)d_in[7];
    const float* W_ih   = (const float*)d_in[8];
    const float* W_hh_f = (const float*)d_in[9];
    const float* b_ih   = (const float*)d_in[10];
    const float* b_hh   = (const float*)d_in[11];
    const float* betaW  = (const float*)d_in[12];
    const float* betab  = (const float*)d_in[13];
    const float* gammaW = (const float*)d_in[14];
    const float* gammab = (const float*)d_in[15];
    const float* sigmaW = (const float*)d_in[16];
    const float* sigmab = (const float*)d_in[17];
    float* out = (float*)d_out;

    size_t off = 0;
    char* ws = (char*)d_ws;
    auto alloc = [&](size_t bytes) { void* p = ws + off; off += (bytes + 255) & ~(size_t)255; return p; };
    __bf16* XWb  = (__bf16*)alloc((size_t)Bn*TM1*512*2);
    __bf16* Xbf  = (__bf16*)alloc((size_t)Bn*TM1*512*2);
    __bf16* Wdc  = (__bf16*)alloc((size_t)512*1024*2);
    __bf16* W1x  = (__bf16*)alloc((size_t)512*512*2);
    __bf16* Whh  = (__bf16*)alloc((size_t)2048*512*2);
    float*  cf   = (float*)alloc((size_t)Bn*512*4);
    float*  df   = (float*)alloc((size_t)Bn*512*4);
    float*  dcWp = (float*)alloc((size_t)2*512*512*4);
    float*  dWhh = (float*)alloc((size_t)Bn*2048*4);
    float*  bsum = (float*)alloc((size_t)2048*4);
    float*  XF   = (float*)alloc((size_t)Bn*TM1*4);
    float*  b62  = (float*)alloc((size_t)Bn*64*4);
    unsigned* bar = (unsigned*)alloc(4096);

    // dcb ring: 64 slots if workspace permits (persistent), else 2 (discrete)
    int persist = (ws_size >= off + (size_t)64*SLOT*2 + 256) ? 1 : 0;
    __bf16* dcbRing = (__bf16*)alloc((size_t)(persist ? 64 : 2)*SLOT*2);

    hipMemsetAsync(dcbRing, 0, (size_t)SLOT*2, stream);
    hipMemsetAsync(cf,  0, (size_t)Bn*512*4, stream);
    hipMemsetAsync(bar, 0, 4096, stream);

    k_prep_weights<<<512, 256, 0, stream>>>(W1, W_hh_f, b_ih, b_hh, Wdc, W1x, Whh, bsum);
    int nx = Bn*TM1*512;
    k_conv_x<<<(nx/4 + 255)/256, 256, 0, stream>>>(X, Xbf, nx);
    k_xf<<<(Bn*TM1 + 31)/32, 256, 0, stream>>>(Xbf, fcW, XF);
    k_gemm_xw<<<(Bn*TM1/64)*8, 256, 0, stream>>>(Xbf, W1x, b1, XWb);

    if (persist) {
        PParams pp;
        pp.Wdc = Wdc; pp.Whh = Whh; pp.XWb = XWb;
        pp.XF = XF; pp.y_prev = y_prev; pp.W2 = W2; pp.fcW = fcW; pp.fcb = fcb;
        pp.W_ih = W_ih; pp.bsum = bsum;
        pp.dcWp = dcWp; pp.dWhh_ = dWhh; pp.cf = cf; pp.df = df; pp.b62 = b62;
        pp.dcbRing = dcbRing; pp.bar = bar;
        k_persist<<<NBLK, 256, 0, stream>>>(pp);
    } else {
        for (int t = 0; t < TM1; ++t) {
            const __bf16* rd = dcbRing + (size_t)(t & 1)*SLOT;
            __bf16* wr = dcbRing + (size_t)((t + 1) & 1)*SLOT;
            k_stepA<<<384, 256, 0, stream>>>(rd, Wdc, Whh, dcWp, dWhh);
            k_stepB<<<Bn, 256, 0, stream>>>(t, dcWp, dWhh, XWb, XF, y_prev, W2,
                                            fcW, fcb, W_ih, bsum, cf, df, wr, b62);
        }
    }
    k_finish<<<Bn, 512, 0, stream>>>(b62, Xbf, df,
                                     betaW, betab, sigmaW, sigmab, gammaW, gammab, out);
}

// Round 13
// 1675.003 us; speedup vs baseline: 3.8906x; 1.1840x over previous
//
#include <hip/hip_runtime.h>

typedef __bf16 bf16x8 __attribute__((ext_vector_type(8)));
typedef float  f32x4  __attribute__((ext_vector_type(4)));

#define Bn  512
#define TM1 63

__device__ __forceinline__ float fast_rcp(float x){ return __builtin_amdgcn_rcpf(x); }
__device__ __forceinline__ float fast_tanh(float x){
    float e = __expf(2.0f*x);
    return 1.0f - 2.0f*fast_rcp(e + 1.0f);
}
__device__ __forceinline__ float fast_sigmoid(float x){
    return fast_rcp(1.0f + __expf(-x));
}

// async global->LDS, 16B per lane; lds ptr must be wave-uniform (HW adds lane*16)
__device__ __forceinline__ void gll16(const __bf16* g, __bf16* l) {
    __builtin_amdgcn_global_load_lds(
        (const __attribute__((address_space(1))) unsigned int*)(g),
        (__attribute__((address_space(3))) unsigned int*)(l),
        16, 0, 0);
}

// ---------------- setup kernels ----------------

__global__ __launch_bounds__(256) void k_prep_weights(
    const float* __restrict__ W1, const float* __restrict__ Whh_f,
    const float* __restrict__ b_ih, const float* __restrict__ b_hh,
    __bf16* __restrict__ Wdc, __bf16* __restrict__ W1x, __bf16* __restrict__ Whh,
    float* __restrict__ bsum)
{
    int i = blockIdx.x*256 + threadIdx.x;
    int n = gridDim.x*256;
    for (int idx = i; idx < 512*1024; idx += n) {
        int f = idx >> 10, k = idx & 1023;
        Wdc[idx] = (__bf16)W1[f*1536 + k];
    }
    for (int idx = i; idx < 512*512; idx += n) {
        int f = idx >> 9, k = idx & 511;
        W1x[idx] = (__bf16)W1[f*1536 + 1024 + k];
    }
    for (int idx = i; idx < 2048*512; idx += n) {
        Whh[idx] = (__bf16)Whh_f[idx];
    }
    for (int idx = i; idx < 2048; idx += n) {
        bsum[idx] = b_ih[idx] + b_hh[idx];
    }
}

__global__ __launch_bounds__(256) void k_conv_x(const float* __restrict__ X, __bf16* __restrict__ Xb, int n)
{
    int idx = (blockIdx.x*256 + threadIdx.x)*4;
    if (idx < n) {
        float4 v = *(const float4*)(X + idx);
        Xb[idx+0] = (__bf16)v.x; Xb[idx+1] = (__bf16)v.y;
        Xb[idx+2] = (__bf16)v.z; Xb[idx+3] = (__bf16)v.w;
    }
}

// XF[m] = sum_e Xbf[m,e]*fcW[e]
__global__ __launch_bounds__(256) void k_xf(
    const __bf16* __restrict__ Xbf, const float* __restrict__ fcW, float* __restrict__ XF)
{
    int lane = threadIdx.x & 63, wave = threadIdx.x >> 6;
    float fcr[8];
    {
        const float4* fp = (const float4*)(fcW + lane*8);
        float4 f0 = fp[0], f1 = fp[1];
        fcr[0]=f0.x; fcr[1]=f0.y; fcr[2]=f0.z; fcr[3]=f0.w;
        fcr[4]=f1.x; fcr[5]=f1.y; fcr[6]=f1.z; fcr[7]=f1.w;
    }
    int row0 = (blockIdx.x*4 + wave)*8;
    #pragma unroll
    for (int j = 0; j < 8; ++j) {
        int row = row0 + j;
        if (row >= Bn*TM1) break;
        bf16x8 x = *(const bf16x8*)(Xbf + (size_t)row*512 + lane*8);
        float p = 0.f;
        #pragma unroll
        for (int i=0;i<8;i++) p += fcr[i]*(float)x[i];
        #pragma unroll
        for (int o=32;o;o>>=1) p += __shfl_xor(p,o,64);
        if (lane==0) XF[row] = p;
    }
}

// ---------------- LDS-staged 64x64-tile GEMM body (XOR-swizzled) ----------------
// C[row,col] = sum_k A[row,k]*B[col,k]; 256 threads, 4 waves, 32x32/wave.
// BK=64, double-buffered LDS, global_load_lds staging, 1 barrier/K-step.
// Swizzle (both sides, rule #21): LDS 16B-chunk j of row r holds global chunk j^(r&7).
template <int ADDBIAS>
__device__ __forceinline__ void gemm_tile_lds(
    const __bf16* __restrict__ A, const __bf16* __restrict__ Bm,
    const float* __restrict__ bias, void* __restrict__ C, int as_bf16,
    int row0, int col0, int K, int lda, int ldb, int ldc,
    __bf16* sA, __bf16* sB)   // each 2*4096 elems
{
    int lane = threadIdx.x & 63, wave = threadIdx.x >> 6;
    int wr = wave >> 1, wc = wave & 1;
    int l15 = lane & 15, l4 = lane >> 4;
    int lr = lane >> 3;                      // row-in-chunk 0..7
    int lcs = ((lane & 7) ^ lr) * 8;         // inverse-swizzled source column (elements)

    auto stage = [&](int buf, int kt) {
        int k0 = kt*64;
        #pragma unroll
        for (int j = 0; j < 2; ++j) {
            int c = wave*2 + j;          // chunk 0..7, rows [c*8, c*8+8)
            int grow = c*8 + lr;
            gll16(A  + (size_t)(row0+grow)*lda + k0 + lcs, sA + buf*4096 + c*512);
            gll16(Bm + (size_t)(col0+grow)*ldb + k0 + lcs, sB + buf*4096 + c*512);
        }
    };

    int NT = K >> 6;
    stage(0, 0);
    f32x4 acc[2][2] = {};
    int s7 = l15 & 7;
    const __bf16* aRow = sA + (wr*32 + l15)*64;
    const __bf16* bRow = sB + (wc*32 + l15)*64;
    for (int kt = 0; kt < NT; ++kt) {
        int buf = kt & 1;
        asm volatile("s_waitcnt vmcnt(0)");
        __syncthreads();
        if (kt + 1 < NT) stage(buf ^ 1, kt + 1);
        #pragma unroll
        for (int kk = 0; kk < 2; ++kk) {
            int ch = ((l4 + kk*4) ^ s7) * 8;
            bf16x8 a0 = *(const bf16x8*)(aRow + buf*4096 + ch);
            bf16x8 a1 = *(const bf16x8*)(aRow + buf*4096 + 16*64 + ch);
            bf16x8 b0 = *(const bf16x8*)(bRow + buf*4096 + ch);
            bf16x8 b1 = *(const bf16x8*)(bRow + buf*4096 + 16*64 + ch);
            acc[0][0] = __builtin_amdgcn_mfma_f32_16x16x32_bf16(a0,b0,acc[0][0],0,0,0);
            acc[0][1] = __builtin_amdgcn_mfma_f32_16x16x32_bf16(a0,b1,acc[0][1],0,0,0);
            acc[1][0] = __builtin_amdgcn_mfma_f32_16x16x32_bf16(a1,b0,acc[1][0],0,0,0);
            acc[1][1] = __builtin_amdgcn_mfma_f32_16x16x32_bf16(a1,b1,acc[1][1],0,0,0);
        }
    }
    int row_a = row0 + wr*32;
    int col_b = col0 + wc*32;
    #pragma unroll
    for (int mi=0; mi<2; mi++)
    #pragma unroll
    for (int ni=0; ni<2; ni++) {
        int r0 = row_a + mi*16 + l4*4;
        int c0 = col_b + ni*16 + l15;
        float bv = ADDBIAS ? bias[c0] : 0.f;
        if (as_bf16) {
            __bf16* Cb = (__bf16*)C;
            #pragma unroll
            for (int r=0; r<4; r++)
                Cb[(size_t)(r0+r)*ldc + c0] = (__bf16)(acc[mi][ni][r] + bv);
        } else {
            float* Cf = (float*)C;
            #pragma unroll
            for (int r=0; r<4; r++)
                Cf[(size_t)(r0+r)*ldc + c0] = acc[mi][ni][r];
        }
    }
}

// XW[m,f] = sum_e Xbf[m,e]*W1x[f,e] + b1[f]; M=32256,N=512,K=512
__global__ __launch_bounds__(256) void k_gemm_xw(
    const __bf16* __restrict__ A, const __bf16* __restrict__ Bm,
    const float* __restrict__ bias, __bf16* __restrict__ C)
{
    __shared__ __bf16 sA[2*4096], sB[2*4096];
    // XCD-chunked bijective swizzle: 4032 blocks = 8 XCDs x 504
    int orig = (blockIdx.x & 7)*504 + (blockIdx.x >> 3);
    int tm = orig >> 3, tn = orig & 7;
    gemm_tile_lds<1>(A, Bm, bias, C, 1, tm*64, tn*64, 512, 512, 512, 512, sA, sB);
}

// blocks 0..63:   dcW [512x512]   = dc[512x1024k] @ Wdc[512n x 1024k]^T
// blocks 64..319: dWhh [512x2048] = d [512x512k]  @ Whh[2048n x 512k]^T  (d = dc rows, lda=1024)
__global__ __launch_bounds__(256) void k_step_gemm(
    const __bf16* __restrict__ dc, const __bf16* __restrict__ Wdc,
    const __bf16* __restrict__ Whh, float* __restrict__ dcW, float* __restrict__ dWhh)
{
    __shared__ __bf16 sA[2*4096], sB[2*4096];
    int blk = blockIdx.x;
    if (blk < 64) {
        int tm = blk >> 3, tn = blk & 7;
        gemm_tile_lds<0>(dc, Wdc, nullptr, dcW, 0, tm*64, tn*64, 1024, 1024, 1024, 512, sA, sB);
    } else {
        int b2 = blk - 64;
        int tm = b2 >> 5, tn = b2 & 31;
        gemm_tile_lds<0>(dc, Whh, nullptr, dWhh, 0, tm*64, tn*64, 512, 1024, 512, 2048, sA, sB);
    }
}

// ---------------- per-step fused kernel ----------------

// one block (512 threads) per batch row; no ctx phase (XF trick)
#define PSTR 76   // s_part row stride (floats)
__global__ __launch_bounds__(512) void k_step_fused(
    int t,
    const float* __restrict__ dcW, const float* __restrict__ dWhh,
    const __bf16* __restrict__ XWb, const float* __restrict__ XF,
    const float* __restrict__ y_prev, const float* __restrict__ W2,
    const float* __restrict__ fcW, const float* __restrict__ fcb,
    const float* __restrict__ W_ih, const float* __restrict__ bsum,
    float* __restrict__ c_f32, float* __restrict__ d_f32,
    __bf16* __restrict__ dc_bf16, float* __restrict__ beta_out)
{
    int b = blockIdx.x;
    int tid = threadIdx.x, lane = tid & 63, wave = tid >> 6;
    __shared__ float s_part[64*PSTR];
    __shared__ float s_sc[64];
    __shared__ float s_y;

    // ---- HOIST (R12 change): gate-phase operands are independent of the
    // scores/softmax phases -> issue their loads first so ~500cy of L2/L3
    // latency hides under the tanh/score work instead of stalling the tail.
    size_t gb = (size_t)b*2048 + tid;
    float pg_i = dWhh[gb];
    float pg_f = dWhh[gb + 512];
    float pg_g = dWhh[gb + 1024];
    float pg_o = dWhh[gb + 1536];
    float wi_i = W_ih[tid];
    float wi_f = W_ih[512 + tid];
    float wi_g = W_ih[1024 + tid];
    float wi_o = W_ih[1536 + tid];
    float bs_i = bsum[tid];
    float bs_f = bsum[512 + tid];
    float bs_g = bsum[1024 + tid];
    float bs_o = bsum[1536 + tid];
    float c_old = c_f32[(size_t)b*512 + tid];

    // hoist per-lane W2 / dcW slices into registers (same f-slice for all 8 t's)
    float w2r[8], dr[8];
    {
        const float4* w2p = (const float4*)(W2 + lane*8);
        const float4* dp  = (const float4*)(dcW + (size_t)b*512 + lane*8);
        float4 w0 = w2p[0], w1 = w2p[1], e0v = dp[0], e1v = dp[1];
        w2r[0]=w0.x; w2r[1]=w0.y; w2r[2]=w0.z; w2r[3]=w0.w;
        w2r[4]=w1.x; w2r[5]=w1.y; w2r[6]=w1.z; w2r[7]=w1.w;
        dr[0]=e0v.x; dr[1]=e0v.y; dr[2]=e0v.z; dr[3]=e0v.w;
        dr[4]=e1v.x; dr[5]=e1v.y; dr[6]=e1v.z; dr[7]=e1v.w;
    }
    // ---- scores: wave w -> t in {w*8..w*8+7}, lane = f-slice (coalesced 1KB/row) ----
    {
        const __bf16* xwp = XWb + ((size_t)b*TM1 + wave*8)*512 + lane*8;
        #pragma unroll
        for (int j = 0; j < 8; ++j) {
            int tt = wave*8 + j;
            float p = 0.f;
            if (tt < TM1) {
                bf16x8 xw = *(const bf16x8*)(xwp + (size_t)j*512);
                #pragma unroll
                for (int i=0;i<8;i++) p += w2r[i]*fast_tanh(dr[i] + (float)xw[i]);
            }
            s_part[tt*PSTR + lane] = p;
        }
    }
    __syncthreads();
    // ---- batched cross-lane reduce: thread -> (tt = tid>>3, g = tid&7) ----
    {
        int tt = tid >> 3, g = tid & 7;
        const float4* pp = (const float4*)(s_part + tt*PSTR + g*8);
        float4 u0 = pp[0], u1 = pp[1];
        float r = u0.x+u0.y+u0.z+u0.w + u1.x+u1.y+u1.z+u1.w;
        r += __shfl_xor(r, 1, 64);
        r += __shfl_xor(r, 2, 64);
        r += __shfl_xor(r, 4, 64);
        if (g == 0) s_sc[tt] = r;
    }
    __syncthreads();
    // ---- softmax over 63 + y via XF dot (wave 0); no max pass (|s| <= sum|W2| ~ 19) ----
    if (wave == 0) {
        float e = (lane < TM1) ? __expf(s_sc[lane]) : 0.f;
        float sum = e;
        #pragma unroll
        for (int o=32;o;o>>=1) sum += __shfl_xor(sum,o,64);
        float beta = e*fast_rcp(sum);      // lane 63 -> 0
        if (t == 62) beta_out[b*64 + lane] = beta;
        float yp = (lane < TM1) ? beta*XF[(size_t)b*TM1 + lane] : 0.f;
        #pragma unroll
        for (int o=32;o;o>>=1) yp += __shfl_xor(yp,o,64);
        if (lane == 0)
            s_y = yp + fcW[512]*y_prev[(size_t)b*TM1 + t] + fcb[0];
    }
    __syncthreads();
    float yv = s_y;
    // ---- gates + state update: k = tid (operands preloaded at top) ----
    {
        int k = tid;
        float gi = pg_i + yv*wi_i + bs_i;
        float gf = pg_f + yv*wi_f + bs_f;
        float gg = pg_g + yv*wi_g + bs_g;
        float go = pg_o + yv*wi_o + bs_o;
        size_t sk = (size_t)b*512 + k;
        float cn = fast_sigmoid(gf)*c_old + fast_sigmoid(gi)*fast_tanh(gg);
        float dn = fast_sigmoid(go)*fast_tanh(cn);
        c_f32[sk] = cn; d_f32[sk] = dn;
        dc_bf16[(size_t)b*1024 + k]       = (__bf16)dn;
        dc_bf16[(size_t)b*1024 + 512 + k] = (__bf16)cn;
    }
}

// ---------------- finish: ctx_last from beta(62) + heads ----------------
// out[0:512]=beta, [512:1024]=sigma, [1024:1536]=gamma
__global__ __launch_bounds__(512) void k_finish(
    const float* __restrict__ beta62, const __bf16* __restrict__ Xbf,
    const float* __restrict__ d_f32,
    const float* __restrict__ bW, const float* __restrict__ bb,
    const float* __restrict__ sW, const float* __restrict__ sb,
    const float* __restrict__ gW, const float* __restrict__ gb,
    float* __restrict__ out)
{
    int b = blockIdx.x;
    int tid = threadIdx.x, lane = tid & 63, wave = tid >> 6;
    __shared__ float s_beta[64];
    __shared__ float s_red[3][8];
    if (tid < 64) s_beta[tid] = beta62[b*64 + tid];
    __syncthreads();
    // ctx[e=tid] = sum_t beta[t] X[b,t,e]  (coalesced 2B loads, 63 independent)
    float ctxv = 0.f;
    {
        const __bf16* xp = Xbf + (size_t)b*TM1*512 + tid;
        #pragma unroll
        for (int tt = 0; tt < TM1; ++tt)
            ctxv += s_beta[tt]*(float)xp[(size_t)tt*512];
    }
    float dv = d_f32[(size_t)b*512 + tid];
    float pb = bW[tid]*dv + bW[512+tid]*ctxv;
    float ps = sW[tid]*dv + sW[512+tid]*ctxv;
    float pg = gW[tid]*dv + gW[512+tid]*ctxv;
    #pragma unroll
    for (int o=32;o;o>>=1) {
        pb += __shfl_xor(pb,o,64); ps += __shfl_xor(ps,o,64); pg += __shfl_xor(pg,o,64);
    }
    if (lane==0) { s_red[0][wave]=pb; s_red[1][wave]=ps; s_red[2][wave]=pg; }
    __syncthreads();
    if (tid==0) {
        float sb_=0,ss_=0,sg_=0;
        #pragma unroll
        for (int w=0;w<8;w++){ sb_+=s_red[0][w]; ss_+=s_red[1][w]; sg_+=s_red[2][w]; }
        out[b]        = sb_ + bb[0];
        out[512 + b]  = ss_ + sb[0];
        out[1024 + b] = sg_ + gb[0];
    }
}

extern "C" void kernel_launch(void* const* d_in, const int* in_sizes, int n_in,
                              void* d_out, int out_size, void* d_ws, size_t ws_size,
                              hipStream_t stream) {
    const float* X      = (const float*)d_in[0];
    const float* y_prev = (const float*)d_in[1];
    const float* W1     = (const float*)d_in[2];
    const float* b1     = (const float*)d_in[3];
    const float* W2     = (const float*)d_in[4];
    // d_in[5] = attn_b2 (softmax-invariant constant shift, skipped)
    const float* fcW    = (const float*)d_in[6];
    const float* fcb    = (const float*)d_in[7];
    const float* W_ih   = (const float*)d_in[8];
    const float* W_hh_f = (const float*)d_in[9];
    const float* b_ih   = (const float*)d_in[10];
    const float* b_hh   = (const float*)d_in[11];
    const float* betaW  = (const float*)d_in[12];
    const float* betab  = (const float*)d_in[13];
    const float* gammaW = (const float*)d_in[14];
    const float* gammab = (const float*)d_in[15];
    const float* sigmaW = (const float*)d_in[16];
    const float* sigmab = (const float*)d_in[17];
    float* out = (float*)d_out;

    size_t off = 0;
    char* ws = (char*)d_ws;
    auto alloc = [&](size_t bytes) { void* p = ws + off; off += (bytes + 255) & ~(size_t)255; return p; };
    __bf16* XWb  = (__bf16*)alloc((size_t)Bn*TM1*512*2);
    __bf16* Xbf  = (__bf16*)alloc((size_t)Bn*TM1*512*2);
    __bf16* Wdc  = (__bf16*)alloc((size_t)512*1024*2);
    __bf16* W1x  = (__bf16*)alloc((size_t)512*512*2);
    __bf16* Whh  = (__bf16*)alloc((size_t)2048*512*2);
    __bf16* dcb  = (__bf16*)alloc((size_t)Bn*1024*2);
    float*  cf   = (float*)alloc((size_t)Bn*512*4);
    float*  df   = (float*)alloc((size_t)Bn*512*4);
    float*  dcW  = (float*)alloc((size_t)Bn*512*4);
    float*  dWhh = (float*)alloc((size_t)Bn*2048*4);
    float*  bsum = (float*)alloc((size_t)2048*4);
    float*  XF   = (float*)alloc((size_t)Bn*TM1*4);
    float*  b62  = (float*)alloc((size_t)Bn*64*4);

    hipMemsetAsync(dcb, 0, (size_t)Bn*1024*2, stream);
    hipMemsetAsync(cf,  0, (size_t)Bn*512*4, stream);

    k_prep_weights<<<512, 256, 0, stream>>>(W1, W_hh_f, b_ih, b_hh, Wdc, W1x, Whh, bsum);
    int nx = Bn*TM1*512;
    k_conv_x<<<(nx/4 + 255)/256, 256, 0, stream>>>(X, Xbf, nx);
    k_xf<<<(Bn*TM1 + 31)/32, 256, 0, stream>>>(Xbf, fcW, XF);
    k_gemm_xw<<<(Bn*TM1/64)*8, 256, 0, stream>>>(Xbf, W1x, b1, XWb);

    for (int t = 0; t < TM1; ++t) {
        k_step_gemm<<<320, 256, 0, stream>>>(dcb, Wdc, Whh, dcW, dWhh);
        k_step_fused<<<Bn, 512, 0, stream>>>(t, dcW, dWhh, XWb, XF, y_prev, W2,
                                             fcW, fcb, W_ih, bsum,
                                             cf, df, dcb, b62);
    }
    k_finish<<<Bn, 512, 0, stream>>>(b62, Xbf, df,
                                     betaW, betab, sigmaW, sigmab, gammaW, gammab, out);
}

// Round 14
// 1334.932 us; speedup vs baseline: 4.8818x; 1.2547x over previous
//
#include <hip/hip_runtime.h>

typedef __bf16 bf16x8 __attribute__((ext_vector_type(8)));
typedef float  f32x4  __attribute__((ext_vector_type(4)));

#define Bn  512
#define TM1 63

__device__ __forceinline__ float fast_rcp(float x){ return __builtin_amdgcn_rcpf(x); }
__device__ __forceinline__ float fast_tanh(float x){
    float e = __expf(2.0f*x);
    return 1.0f - 2.0f*fast_rcp(e + 1.0f);
}
__device__ __forceinline__ float fast_sigmoid(float x){
    return fast_rcp(1.0f + __expf(-x));
}

// async global->LDS, 16B per lane; lds ptr must be wave-uniform (HW adds lane*16)
__device__ __forceinline__ void gll16(const __bf16* g, __bf16* l) {
    __builtin_amdgcn_global_load_lds(
        (const __attribute__((address_space(1))) unsigned int*)(g),
        (__attribute__((address_space(3))) unsigned int*)(l),
        16, 0, 0);
}

// ---------------- setup kernels ----------------

__global__ __launch_bounds__(256) void k_prep_weights(
    const float* __restrict__ W1, const float* __restrict__ Whh_f,
    const float* __restrict__ b_ih, const float* __restrict__ b_hh,
    __bf16* __restrict__ Wdc, __bf16* __restrict__ W1x, __bf16* __restrict__ Whh,
    float* __restrict__ bsum)
{
    int i = blockIdx.x*256 + threadIdx.x;
    int n = gridDim.x*256;
    for (int idx = i; idx < 512*1024; idx += n) {
        int f = idx >> 10, k = idx & 1023;
        Wdc[idx] = (__bf16)W1[f*1536 + k];
    }
    for (int idx = i; idx < 512*512; idx += n) {
        int f = idx >> 9, k = idx & 511;
        W1x[idx] = (__bf16)W1[f*1536 + 1024 + k];
    }
    for (int idx = i; idx < 2048*512; idx += n) {
        Whh[idx] = (__bf16)Whh_f[idx];
    }
    for (int idx = i; idx < 2048; idx += n) {
        bsum[idx] = b_ih[idx] + b_hh[idx];
    }
}

__global__ __launch_bounds__(256) void k_conv_x(const float* __restrict__ X, __bf16* __restrict__ Xb, int n)
{
    int idx = (blockIdx.x*256 + threadIdx.x)*4;
    if (idx < n) {
        float4 v = *(const float4*)(X + idx);
        Xb[idx+0] = (__bf16)v.x; Xb[idx+1] = (__bf16)v.y;
        Xb[idx+2] = (__bf16)v.z; Xb[idx+3] = (__bf16)v.w;
    }
}

// XF[m] = sum_e Xbf[m,e]*fcW[e]
__global__ __launch_bounds__(256) void k_xf(
    const __bf16* __restrict__ Xbf, const float* __restrict__ fcW, float* __restrict__ XF)
{
    int lane = threadIdx.x & 63, wave = threadIdx.x >> 6;
    float fcr[8];
    {
        const float4* fp = (const float4*)(fcW + lane*8);
        float4 f0 = fp[0], f1 = fp[1];
        fcr[0]=f0.x; fcr[1]=f0.y; fcr[2]=f0.z; fcr[3]=f0.w;
        fcr[4]=f1.x; fcr[5]=f1.y; fcr[6]=f1.z; fcr[7]=f1.w;
    }
    int row0 = (blockIdx.x*4 + wave)*8;
    #pragma unroll
    for (int j = 0; j < 8; ++j) {
        int row = row0 + j;
        if (row >= Bn*TM1) break;
        bf16x8 x = *(const bf16x8*)(Xbf + (size_t)row*512 + lane*8);
        float p = 0.f;
        #pragma unroll
        for (int i=0;i<8;i++) p += fcr[i]*(float)x[i];
        #pragma unroll
        for (int o=32;o;o>>=1) p += __shfl_xor(p,o,64);
        if (lane==0) XF[row] = p;
    }
}

// ---------------- LDS-staged 64x64-tile GEMM body (XOR-swizzled) ----------------
// C[row,col] = sum_k A[row,k]*B[col,k]; 256 threads, 4 waves, 32x32/wave.
// BK=64, double-buffered LDS, global_load_lds staging, 1 barrier/K-step.
// Swizzle (both sides, rule #21): LDS 16B-chunk j of row r holds global chunk j^(r&7).
template <int ADDBIAS>
__device__ __forceinline__ void gemm_tile_lds(
    const __bf16* __restrict__ A, const __bf16* __restrict__ Bm,
    const float* __restrict__ bias, void* __restrict__ C, int as_bf16,
    int row0, int col0, int K, int lda, int ldb, int ldc,
    __bf16* sA, __bf16* sB)   // each 2*4096 elems
{
    int lane = threadIdx.x & 63, wave = threadIdx.x >> 6;
    int wr = wave >> 1, wc = wave & 1;
    int l15 = lane & 15, l4 = lane >> 4;
    int lr = lane >> 3;                      // row-in-chunk 0..7
    int lcs = ((lane & 7) ^ lr) * 8;         // inverse-swizzled source column (elements)

    auto stage = [&](int buf, int kt) {
        int k0 = kt*64;
        #pragma unroll
        for (int j = 0; j < 2; ++j) {
            int c = wave*2 + j;          // chunk 0..7, rows [c*8, c*8+8)
            int grow = c*8 + lr;
            gll16(A  + (size_t)(row0+grow)*lda + k0 + lcs, sA + buf*4096 + c*512);
            gll16(Bm + (size_t)(col0+grow)*ldb + k0 + lcs, sB + buf*4096 + c*512);
        }
    };

    int NT = K >> 6;
    stage(0, 0);
    f32x4 acc[2][2] = {};
    int s7 = l15 & 7;
    const __bf16* aRow = sA + (wr*32 + l15)*64;
    const __bf16* bRow = sB + (wc*32 + l15)*64;
    for (int kt = 0; kt < NT; ++kt) {
        int buf = kt & 1;
        asm volatile("s_waitcnt vmcnt(0)");
        __syncthreads();
        if (kt + 1 < NT) stage(buf ^ 1, kt + 1);
        #pragma unroll
        for (int kk = 0; kk < 2; ++kk) {
            int ch = ((l4 + kk*4) ^ s7) * 8;
            bf16x8 a0 = *(const bf16x8*)(aRow + buf*4096 + ch);
            bf16x8 a1 = *(const bf16x8*)(aRow + buf*4096 + 16*64 + ch);
            bf16x8 b0 = *(const bf16x8*)(bRow + buf*4096 + ch);
            bf16x8 b1 = *(const bf16x8*)(bRow + buf*4096 + 16*64 + ch);
            acc[0][0] = __builtin_amdgcn_mfma_f32_16x16x32_bf16(a0,b0,acc[0][0],0,0,0);
            acc[0][1] = __builtin_amdgcn_mfma_f32_16x16x32_bf16(a0,b1,acc[0][1],0,0,0);
            acc[1][0] = __builtin_amdgcn_mfma_f32_16x16x32_bf16(a1,b0,acc[1][0],0,0,0);
            acc[1][1] = __builtin_amdgcn_mfma_f32_16x16x32_bf16(a1,b1,acc[1][1],0,0,0);
        }
    }
    int row_a = row0 + wr*32;
    int col_b = col0 + wc*32;
    #pragma unroll
    for (int mi=0; mi<2; mi++)
    #pragma unroll
    for (int ni=0; ni<2; ni++) {
        int r0 = row_a + mi*16 + l4*4;
        int c0 = col_b + ni*16 + l15;
        float bv = ADDBIAS ? bias[c0] : 0.f;
        if (as_bf16) {
            __bf16* Cb = (__bf16*)C;
            #pragma unroll
            for (int r=0; r<4; r++)
                Cb[(size_t)(r0+r)*ldc + c0] = (__bf16)(acc[mi][ni][r] + bv);
        } else {
            float* Cf = (float*)C;
            #pragma unroll
            for (int r=0; r<4; r++)
                Cf[(size_t)(r0+r)*ldc + c0] = acc[mi][ni][r];
        }
    }
}

// XW[m,f] = sum_e Xbf[m,e]*W1x[f,e] + b1[f]; M=32256,N=512,K=512
__global__ __launch_bounds__(256) void k_gemm_xw(
    const __bf16* __restrict__ A, const __bf16* __restrict__ Bm,
    const float* __restrict__ bias, __bf16* __restrict__ C)
{
    __shared__ __bf16 sA[2*4096], sB[2*4096];
    // XCD-chunked bijective swizzle: 4032 blocks = 8 XCDs x 504
    int orig = (blockIdx.x & 7)*504 + (blockIdx.x >> 3);
    int tm = orig >> 3, tn = orig & 7;
    gemm_tile_lds<1>(A, Bm, bias, C, 1, tm*64, tn*64, 512, 512, 512, 512, sA, sB);
}

// 384 UNIFORM K=512 jobs (R13 change: split dcW's K=1024 into 2 halves to kill
// the long-job straggler tail; halves summed in k_step_fused, proven in R10).
// blocks 0..127:  dcWp[kh][512][512] = dc[:, kh*512:+512] @ Wdc[:, kh*512:+512]^T
// blocks 128..383: dWhh [512x2048]   = d [512x512k] @ Whh[2048n x 512k]^T
__global__ __launch_bounds__(256) void k_step_gemm(
    const __bf16* __restrict__ dc, const __bf16* __restrict__ Wdc,
    const __bf16* __restrict__ Whh, float* __restrict__ dcWp, float* __restrict__ dWhh)
{
    __shared__ __bf16 sA[2*4096], sB[2*4096];
    int blk = blockIdx.x;
    if (blk < 128) {
        int kh = blk & 1, tt = blk >> 1;
        int tm = tt >> 3, tn = tt & 7;
        gemm_tile_lds<0>(dc + kh*512, Wdc + kh*512, nullptr,
                         dcWp + (size_t)kh*512*512, 0,
                         tm*64, tn*64, 512, 1024, 1024, 512, sA, sB);
    } else {
        int b2 = blk - 128;
        int tm = b2 >> 5, tn = b2 & 31;
        gemm_tile_lds<0>(dc, Whh, nullptr, dWhh, 0, tm*64, tn*64, 512, 1024, 512, 2048, sA, sB);
    }
}

// ---------------- per-step fused kernel ----------------

// one block (512 threads) per batch row; no ctx phase (XF trick)
#define PSTR 76   // s_part row stride (floats)
__global__ __launch_bounds__(512) void k_step_fused(
    int t,
    const float* __restrict__ dcWp, const float* __restrict__ dWhh,
    const __bf16* __restrict__ XWb, const float* __restrict__ XF,
    const float* __restrict__ y_prev, const float* __restrict__ W2,
    const float* __restrict__ fcW, const float* __restrict__ fcb,
    const float* __restrict__ W_ih, const float* __restrict__ bsum,
    float* __restrict__ c_f32, float* __restrict__ d_f32,
    __bf16* __restrict__ dc_bf16, float* __restrict__ beta_out)
{
    int b = blockIdx.x;
    int tid = threadIdx.x, lane = tid & 63, wave = tid >> 6;
    __shared__ float s_part[64*PSTR];
    __shared__ float s_sc[64];
    __shared__ float s_y;

    // gate-phase operands hoisted (independent of scores/softmax; latency hides
    // under the tanh phase)
    size_t gb = (size_t)b*2048 + tid;
    float pg_i = dWhh[gb];
    float pg_f = dWhh[gb + 512];
    float pg_g = dWhh[gb + 1024];
    float pg_o = dWhh[gb + 1536];
    float wi_i = W_ih[tid];
    float wi_f = W_ih[512 + tid];
    float wi_g = W_ih[1024 + tid];
    float wi_o = W_ih[1536 + tid];
    float bs_i = bsum[tid];
    float bs_f = bsum[512 + tid];
    float bs_g = bsum[1024 + tid];
    float bs_o = bsum[1536 + tid];
    float c_old = c_f32[(size_t)b*512 + tid];

    // per-lane W2 / dcW slices in registers; dcW = sum of the 2 split-K halves
    float w2r[8], dr[8];
    {
        const float4* w2p = (const float4*)(W2 + lane*8);
        const float4* d0p = (const float4*)(dcWp + (size_t)b*512 + lane*8);
        const float4* d1p = (const float4*)(dcWp + (size_t)512*512 + (size_t)b*512 + lane*8);
        float4 w0 = w2p[0], w1 = w2p[1];
        float4 a0 = d0p[0], a1 = d0p[1], c0 = d1p[0], c1 = d1p[1];
        w2r[0]=w0.x; w2r[1]=w0.y; w2r[2]=w0.z; w2r[3]=w0.w;
        w2r[4]=w1.x; w2r[5]=w1.y; w2r[6]=w1.z; w2r[7]=w1.w;
        dr[0]=a0.x+c0.x; dr[1]=a0.y+c0.y; dr[2]=a0.z+c0.z; dr[3]=a0.w+c0.w;
        dr[4]=a1.x+c1.x; dr[5]=a1.y+c1.y; dr[6]=a1.z+c1.z; dr[7]=a1.w+c1.w;
    }
    // ---- scores: wave w -> t in {w*8..w*8+7}, lane = f-slice (coalesced 1KB/row) ----
    {
        const __bf16* xwp = XWb + ((size_t)b*TM1 + wave*8)*512 + lane*8;
        #pragma unroll
        for (int j = 0; j < 8; ++j) {
            int tt = wave*8 + j;
            float p = 0.f;
            if (tt < TM1) {
                bf16x8 xw = *(const bf16x8*)(xwp + (size_t)j*512);
                #pragma unroll
                for (int i=0;i<8;i++) p += w2r[i]*fast_tanh(dr[i] + (float)xw[i]);
            }
            s_part[tt*PSTR + lane] = p;
        }
    }
    __syncthreads();
    // ---- batched cross-lane reduce: thread -> (tt = tid>>3, g = tid&7) ----
    {
        int tt = tid >> 3, g = tid & 7;
        const float4* pp = (const float4*)(s_part + tt*PSTR + g*8);
        float4 u0 = pp[0], u1 = pp[1];
        float r = u0.x+u0.y+u0.z+u0.w + u1.x+u1.y+u1.z+u1.w;
        r += __shfl_xor(r, 1, 64);
        r += __shfl_xor(r, 2, 64);
        r += __shfl_xor(r, 4, 64);
        if (g == 0) s_sc[tt] = r;
    }
    __syncthreads();
    // ---- softmax over 63 + y via XF dot (wave 0); no max pass (|s| <= sum|W2| ~ 19) ----
    if (wave == 0) {
        float e = (lane < TM1) ? __expf(s_sc[lane]) : 0.f;
        float sum = e;
        #pragma unroll
        for (int o=32;o;o>>=1) sum += __shfl_xor(sum,o,64);
        float beta = e*fast_rcp(sum);      // lane 63 -> 0
        if (t == 62) beta_out[b*64 + lane] = beta;
        float yp = (lane < TM1) ? beta*XF[(size_t)b*TM1 + lane] : 0.f;
        #pragma unroll
        for (int o=32;o;o>>=1) yp += __shfl_xor(yp,o,64);
        if (lane == 0)
            s_y = yp + fcW[512]*y_prev[(size_t)b*TM1 + t] + fcb[0];
    }
    __syncthreads();
    float yv = s_y;
    // ---- gates + state update: k = tid (operands preloaded at top) ----
    {
        int k = tid;
        float gi = pg_i + yv*wi_i + bs_i;
        float gf = pg_f + yv*wi_f + bs_f;
        float gg = pg_g + yv*wi_g + bs_g;
        float go = pg_o + yv*wi_o + bs_o;
        size_t sk = (size_t)b*512 + k;
        float cn = fast_sigmoid(gf)*c_old + fast_sigmoid(gi)*fast_tanh(gg);
        float dn = fast_sigmoid(go)*fast_tanh(cn);
        c_f32[sk] = cn; d_f32[sk] = dn;
        dc_bf16[(size_t)b*1024 + k]       = (__bf16)dn;
        dc_bf16[(size_t)b*1024 + 512 + k] = (__bf16)cn;
    }
}

// ---------------- finish: ctx_last from beta(62) + heads ----------------
// out[0:512]=beta, [512:1024]=sigma, [1024:1536]=gamma
__global__ __launch_bounds__(512) void k_finish(
    const float* __restrict__ beta62, const __bf16* __restrict__ Xbf,
    const float* __restrict__ d_f32,
    const float* __restrict__ bW, const float* __restrict__ bb,
    const float* __restrict__ sW, const float* __restrict__ sb,
    const float* __restrict__ gW, const float* __restrict__ gb,
    float* __restrict__ out)
{
    int b = blockIdx.x;
    int tid = threadIdx.x, lane = tid & 63, wave = tid >> 6;
    __shared__ float s_beta[64];
    __shared__ float s_red[3][8];
    if (tid < 64) s_beta[tid] = beta62[b*64 + tid];
    __syncthreads();
    // ctx[e=tid] = sum_t beta[t] X[b,t,e]  (coalesced 2B loads, 63 independent)
    float ctxv = 0.f;
    {
        const __bf16* xp = Xbf + (size_t)b*TM1*512 + tid;
        #pragma unroll
        for (int tt = 0; tt < TM1; ++tt)
            ctxv += s_beta[tt]*(float)xp[(size_t)tt*512];
    }
    float dv = d_f32[(size_t)b*512 + tid];
    float pb = bW[tid]*dv + bW[512+tid]*ctxv;
    float ps = sW[tid]*dv + sW[512+tid]*ctxv;
    float pg = gW[tid]*dv + gW[512+tid]*ctxv;
    #pragma unroll
    for (int o=32;o;o>>=1) {
        pb += __shfl_xor(pb,o,64); ps += __shfl_xor(ps,o,64); pg += __shfl_xor(pg,o,64);
    }
    if (lane==0) { s_red[0][wave]=pb; s_red[1][wave]=ps; s_red[2][wave]=pg; }
    __syncthreads();
    if (tid==0) {
        float sb_=0,ss_=0,sg_=0;
        #pragma unroll
        for (int w=0;w<8;w++){ sb_+=s_red[0][w]; ss_+=s_red[1][w]; sg_+=s_red[2][w]; }
        out[b]        = sb_ + bb[0];
        out[512 + b]  = ss_ + sb[0];
        out[1024 + b] = sg_ + gb[0];
    }
}

extern "C" void kernel_launch(void* const* d_in, const int* in_sizes, int n_in,
                              void* d_out, int out_size, void* d_ws, size_t ws_size,
                              hipStream_t stream) {
    const float* X      = (const float*)d_in[0];
    const float* y_prev = (const float*)d_in[1];
    const float* W1     = (const float*)d_in[2];
    const float* b1     = (const float*)d_in[3];
    const float* W2     = (const float*)d_in[4];
    // d_in[5] = attn_b2 (softmax-invariant constant shift, skipped)
    const float* fcW    = (const float*)d_in[6];
    const float* fcb    = (const float*)d_in[7];
    const float* W_ih   = (const float*)d_in[8];
    const float* W_hh_f = (const float*)d_in[9];
    const float* b_ih   = (const float*)d_in[10];
    const float* b_hh   = (const float*)d_in[11];
    const float* betaW  = (const float*)d_in[12];
    const float* betab  = (const float*)d_in[13];
    const float* gammaW = (const float*)d_in[14];
    const float* gammab = (const float*)d_in[15];
    const float* sigmaW = (const float*)d_in[16];
    const float* sigmab = (const float*)d_in[17];
    float* out = (float*)d_out;

    size_t off = 0;
    char* ws = (char*)d_ws;
    auto alloc = [&](size_t bytes) { void* p = ws + off; off += (bytes + 255) & ~(size_t)255; return p; };
    __bf16* XWb  = (__bf16*)alloc((size_t)Bn*TM1*512*2);
    __bf16* Xbf  = (__bf16*)alloc((size_t)Bn*TM1*512*2);
    __bf16* Wdc  = (__bf16*)alloc((size_t)512*1024*2);
    __bf16* W1x  = (__bf16*)alloc((size_t)512*512*2);
    __bf16* Whh  = (__bf16*)alloc((size_t)2048*512*2);
    __bf16* dcb  = (__bf16*)alloc((size_t)Bn*1024*2);
    float*  cf   = (float*)alloc((size_t)Bn*512*4);
    float*  df   = (float*)alloc((size_t)Bn*512*4);
    float*  dcWp = (float*)alloc((size_t)2*512*512*4);
    float*  dWhh = (float*)alloc((size_t)Bn*2048*4);
    float*  bsum = (float*)alloc((size_t)2048*4);
    float*  XF   = (float*)alloc((size_t)Bn*TM1*4);
    float*  b62  = (float*)alloc((size_t)Bn*64*4);

    hipMemsetAsync(dcb, 0, (size_t)Bn*1024*2, stream);
    hipMemsetAsync(cf,  0, (size_t)Bn*512*4, stream);

    k_prep_weights<<<512, 256, 0, stream>>>(W1, W_hh_f, b_ih, b_hh, Wdc, W1x, Whh, bsum);
    int nx = Bn*TM1*512;
    k_conv_x<<<(nx/4 + 255)/256, 256, 0, stream>>>(X, Xbf, nx);
    k_xf<<<(Bn*TM1 + 31)/32, 256, 0, stream>>>(Xbf, fcW, XF);
    k_gemm_xw<<<(Bn*TM1/64)*8, 256, 0, stream>>>(Xbf, W1x, b1, XWb);

    for (int t = 0; t < TM1; ++t) {
        k_step_gemm<<<384, 256, 0, stream>>>(dcb, Wdc, Whh, dcWp, dWhh);
        k_step_fused<<<Bn, 512, 0, stream>>>(t, dcWp, dWhh, XWb, XF, y_prev, W2,
                                             fcW, fcb, W_ih, bsum,
                                             cf, df, dcb, b62);
    }
    k_finish<<<Bn, 512, 0, stream>>>(b62, Xbf, df,
                                     betaW, betab, sigmaW, sigmab, gammaW, gammab, out);
}

// Round 15
// 1286.477 us; speedup vs baseline: 5.0656x; 1.0377x over previous
//
#include <hip/hip_runtime.h>

typedef __bf16 bf16x8 __attribute__((ext_vector_type(8)));
typedef float  f32x4  __attribute__((ext_vector_type(4)));

#define Bn  512
#define TM1 63

__device__ __forceinline__ float fast_rcp(float x){ return __builtin_amdgcn_rcpf(x); }
__device__ __forceinline__ float fast_tanh(float x){
    float e = __expf(2.0f*x);
    return 1.0f - 2.0f*fast_rcp(e + 1.0f);
}
__device__ __forceinline__ float fast_sigmoid(float x){
    return fast_rcp(1.0f + __expf(-x));
}

// async global->LDS, 16B per lane; lds ptr must be wave-uniform (HW adds lane*16)
__device__ __forceinline__ void gll16(const __bf16* g, __bf16* l) {
    __builtin_amdgcn_global_load_lds(
        (const __attribute__((address_space(1))) unsigned int*)(g),
        (__attribute__((address_space(3))) unsigned int*)(l),
        16, 0, 0);
}

// ---------------- setup kernels ----------------

__global__ __launch_bounds__(256) void k_prep_weights(
    const float* __restrict__ W1, const float* __restrict__ Whh_f,
    const float* __restrict__ b_ih, const float* __restrict__ b_hh,
    __bf16* __restrict__ Wdc, __bf16* __restrict__ W1x, __bf16* __restrict__ Whh,
    float* __restrict__ bsum)
{
    int i = blockIdx.x*256 + threadIdx.x;
    int n = gridDim.x*256;
    for (int idx = i; idx < 512*1024; idx += n) {
        int f = idx >> 10, k = idx & 1023;
        Wdc[idx] = (__bf16)W1[f*1536 + k];
    }
    for (int idx = i; idx < 512*512; idx += n) {
        int f = idx >> 9, k = idx & 511;
        W1x[idx] = (__bf16)W1[f*1536 + 1024 + k];
    }
    for (int idx = i; idx < 2048*512; idx += n) {
        Whh[idx] = (__bf16)Whh_f[idx];
    }
    for (int idx = i; idx < 2048; idx += n) {
        bsum[idx] = b_ih[idx] + b_hh[idx];
    }
}

__global__ __launch_bounds__(256) void k_conv_x(const float* __restrict__ X, __bf16* __restrict__ Xb, int n)
{
    int idx = (blockIdx.x*256 + threadIdx.x)*4;
    if (idx < n) {
        float4 v = *(const float4*)(X + idx);
        Xb[idx+0] = (__bf16)v.x; Xb[idx+1] = (__bf16)v.y;
        Xb[idx+2] = (__bf16)v.z; Xb[idx+3] = (__bf16)v.w;
    }
}

// XF[m] = sum_e Xbf[m,e]*fcW[e]
__global__ __launch_bounds__(256) void k_xf(
    const __bf16* __restrict__ Xbf, const float* __restrict__ fcW, float* __restrict__ XF)
{
    int lane = threadIdx.x & 63, wave = threadIdx.x >> 6;
    float fcr[8];
    {
        const float4* fp = (const float4*)(fcW + lane*8);
        float4 f0 = fp[0], f1 = fp[1];
        fcr[0]=f0.x; fcr[1]=f0.y; fcr[2]=f0.z; fcr[3]=f0.w;
        fcr[4]=f1.x; fcr[5]=f1.y; fcr[6]=f1.z; fcr[7]=f1.w;
    }
    int row0 = (blockIdx.x*4 + wave)*8;
    #pragma unroll
    for (int j = 0; j < 8; ++j) {
        int row = row0 + j;
        if (row >= Bn*TM1) break;
        bf16x8 x = *(const bf16x8*)(Xbf + (size_t)row*512 + lane*8);
        float p = 0.f;
        #pragma unroll
        for (int i=0;i<8;i++) p += fcr[i]*(float)x[i];
        #pragma unroll
        for (int o=32;o;o>>=1) p += __shfl_xor(p,o,64);
        if (lane==0) XF[row] = p;
    }
}

// ---------------- LDS-staged 64x64-tile GEMM body (XOR-swizzled) ----------------
// C[row,col] = sum_k A[row,k]*B[col,k]; 256 threads, 4 waves, 32x32/wave.
// BK=64, double-buffered LDS, global_load_lds staging, 1 barrier/K-step.
// Swizzle (both sides, rule #21): LDS 16B-chunk j of row r holds global chunk j^(r&7).
template <int ADDBIAS>
__device__ __forceinline__ void gemm_tile_lds(
    const __bf16* __restrict__ A, const __bf16* __restrict__ Bm,
    const float* __restrict__ bias, void* __restrict__ C, int as_bf16,
    int row0, int col0, int K, int lda, int ldb, int ldc,
    __bf16* sA, __bf16* sB)   // each 2*4096 elems
{
    int lane = threadIdx.x & 63, wave = threadIdx.x >> 6;
    int wr = wave >> 1, wc = wave & 1;
    int l15 = lane & 15, l4 = lane >> 4;
    int lr = lane >> 3;                      // row-in-chunk 0..7
    int lcs = ((lane & 7) ^ lr) * 8;         // inverse-swizzled source column (elements)

    auto stage = [&](int buf, int kt) {
        int k0 = kt*64;
        #pragma unroll
        for (int j = 0; j < 2; ++j) {
            int c = wave*2 + j;          // chunk 0..7, rows [c*8, c*8+8)
            int grow = c*8 + lr;
            gll16(A  + (size_t)(row0+grow)*lda + k0 + lcs, sA + buf*4096 + c*512);
            gll16(Bm + (size_t)(col0+grow)*ldb + k0 + lcs, sB + buf*4096 + c*512);
        }
    };

    int NT = K >> 6;
    stage(0, 0);
    f32x4 acc[2][2] = {};
    int s7 = l15 & 7;
    const __bf16* aRow = sA + (wr*32 + l15)*64;
    const __bf16* bRow = sB + (wc*32 + l15)*64;
    for (int kt = 0; kt < NT; ++kt) {
        int buf = kt & 1;
        asm volatile("s_waitcnt vmcnt(0)");
        __syncthreads();
        if (kt + 1 < NT) stage(buf ^ 1, kt + 1);
        #pragma unroll
        for (int kk = 0; kk < 2; ++kk) {
            int ch = ((l4 + kk*4) ^ s7) * 8;
            bf16x8 a0 = *(const bf16x8*)(aRow + buf*4096 + ch);
            bf16x8 a1 = *(const bf16x8*)(aRow + buf*4096 + 16*64 + ch);
            bf16x8 b0 = *(const bf16x8*)(bRow + buf*4096 + ch);
            bf16x8 b1 = *(const bf16x8*)(bRow + buf*4096 + 16*64 + ch);
            acc[0][0] = __builtin_amdgcn_mfma_f32_16x16x32_bf16(a0,b0,acc[0][0],0,0,0);
            acc[0][1] = __builtin_amdgcn_mfma_f32_16x16x32_bf16(a0,b1,acc[0][1],0,0,0);
            acc[1][0] = __builtin_amdgcn_mfma_f32_16x16x32_bf16(a1,b0,acc[1][0],0,0,0);
            acc[1][1] = __builtin_amdgcn_mfma_f32_16x16x32_bf16(a1,b1,acc[1][1],0,0,0);
        }
    }
    int row_a = row0 + wr*32;
    int col_b = col0 + wc*32;
    #pragma unroll
    for (int mi=0; mi<2; mi++)
    #pragma unroll
    for (int ni=0; ni<2; ni++) {
        int r0 = row_a + mi*16 + l4*4;
        int c0 = col_b + ni*16 + l15;
        float bv = ADDBIAS ? bias[c0] : 0.f;
        if (as_bf16) {
            __bf16* Cb = (__bf16*)C;
            #pragma unroll
            for (int r=0; r<4; r++)
                Cb[(size_t)(r0+r)*ldc + c0] = (__bf16)(acc[mi][ni][r] + bv);
        } else {
            float* Cf = (float*)C;
            #pragma unroll
            for (int r=0; r<4; r++)
                Cf[(size_t)(r0+r)*ldc + c0] = acc[mi][ni][r];
        }
    }
}

// XW[m,f] = sum_e Xbf[m,e]*W1x[f,e] + b1[f]; M=32256,N=512,K=512
__global__ __launch_bounds__(256) void k_gemm_xw(
    const __bf16* __restrict__ A, const __bf16* __restrict__ Bm,
    const float* __restrict__ bias, __bf16* __restrict__ C)
{
    __shared__ __bf16 sA[2*4096], sB[2*4096];
    // XCD-chunked bijective swizzle: 4032 blocks = 8 XCDs x 504
    int orig = (blockIdx.x & 7)*504 + (blockIdx.x >> 3);
    int tm = orig >> 3, tn = orig & 7;
    gemm_tile_lds<1>(A, Bm, bias, C, 1, tm*64, tn*64, 512, 512, 512, 512, sA, sB);
}

// 768 UNIFORM K=256 jobs = exactly 3 blocks/CU (R14 change: R13's 384 jobs left
// a 2-vs-1 blocks/CU imbalance; worst CU ran 16 K-iter-equivalents, now 12).
// blocks 0..255:  dcWp[kh][512][512], kh=blk&3   (dcW K=1024 in 4 quarters)
// blocks 256..767: dWhhp[kh][512][2048], kh=b2&1 (dWhh K=512 in 2 halves)
__global__ __launch_bounds__(256) void k_step_gemm(
    const __bf16* __restrict__ dc, const __bf16* __restrict__ Wdc,
    const __bf16* __restrict__ Whh, float* __restrict__ dcWp, float* __restrict__ dWhhp)
{
    __shared__ __bf16 sA[2*4096], sB[2*4096];
    int blk = blockIdx.x;
    if (blk < 256) {
        int kh = blk & 3, tt = blk >> 2;
        int tm = tt >> 3, tn = tt & 7;
        gemm_tile_lds<0>(dc + kh*256, Wdc + kh*256, nullptr,
                         dcWp + (size_t)kh*512*512, 0,
                         tm*64, tn*64, 256, 1024, 1024, 512, sA, sB);
    } else {
        int b2 = blk - 256;
        int kh = b2 & 1, tt = b2 >> 1;
        int tm = tt >> 5, tn = tt & 31;
        gemm_tile_lds<0>(dc + kh*256, Whh + kh*256, nullptr,
                         dWhhp + (size_t)kh*512*2048, 0,
                         tm*64, tn*64, 256, 1024, 512, 2048, sA, sB);
    }
}

// ---------------- per-step fused kernel ----------------

// one block (512 threads) per batch row; no ctx phase (XF trick)
#define PSTR 76   // s_part row stride (floats)
__global__ __launch_bounds__(512) void k_step_fused(
    int t,
    const float* __restrict__ dcWp, const float* __restrict__ dWhhp,
    const __bf16* __restrict__ XWb, const float* __restrict__ XF,
    const float* __restrict__ y_prev, const float* __restrict__ W2,
    const float* __restrict__ fcW, const float* __restrict__ fcb,
    const float* __restrict__ W_ih, const float* __restrict__ bsum,
    float* __restrict__ c_f32, float* __restrict__ d_f32,
    __bf16* __restrict__ dc_bf16, float* __restrict__ beta_out)
{
    int b = blockIdx.x;
    int tid = threadIdx.x, lane = tid & 63, wave = tid >> 6;
    __shared__ float s_part[64*PSTR];
    __shared__ float s_sc[64];
    __shared__ float s_y;

    // gate-phase operands hoisted (independent of scores/softmax; latency hides
    // under the tanh phase). dWhh = sum of 2 split-K halves.
    size_t gb = (size_t)b*2048 + tid;
    const float* dW0 = dWhhp;
    const float* dW1 = dWhhp + (size_t)512*2048;
    float pg_i = dW0[gb]        + dW1[gb];
    float pg_f = dW0[gb + 512]  + dW1[gb + 512];
    float pg_g = dW0[gb + 1024] + dW1[gb + 1024];
    float pg_o = dW0[gb + 1536] + dW1[gb + 1536];
    float wi_i = W_ih[tid];
    float wi_f = W_ih[512 + tid];
    float wi_g = W_ih[1024 + tid];
    float wi_o = W_ih[1536 + tid];
    float bs_i = bsum[tid];
    float bs_f = bsum[512 + tid];
    float bs_g = bsum[1024 + tid];
    float bs_o = bsum[1536 + tid];
    float c_old = c_f32[(size_t)b*512 + tid];

    // per-lane W2 / dcW slices in registers; dcW = sum of the 4 split-K quarters
    float w2r[8], dr[8];
    {
        const float4* w2p = (const float4*)(W2 + lane*8);
        float4 w0 = w2p[0], w1 = w2p[1];
        w2r[0]=w0.x; w2r[1]=w0.y; w2r[2]=w0.z; w2r[3]=w0.w;
        w2r[4]=w1.x; w2r[5]=w1.y; w2r[6]=w1.z; w2r[7]=w1.w;
        #pragma unroll
        for (int i=0;i<8;i++) dr[i] = 0.f;
        #pragma unroll
        for (int q=0;q<4;q++) {
            const float4* dp = (const float4*)(dcWp + (size_t)q*512*512 + (size_t)b*512 + lane*8);
            float4 a0 = dp[0], a1 = dp[1];
            dr[0]+=a0.x; dr[1]+=a0.y; dr[2]+=a0.z; dr[3]+=a0.w;
            dr[4]+=a1.x; dr[5]+=a1.y; dr[6]+=a1.z; dr[7]+=a1.w;
        }
    }
    // ---- scores: wave w -> t in {w*8..w*8+7}, lane = f-slice (coalesced 1KB/row) ----
    {
        const __bf16* xwp = XWb + ((size_t)b*TM1 + wave*8)*512 + lane*8;
        #pragma unroll
        for (int j = 0; j < 8; ++j) {
            int tt = wave*8 + j;
            float p = 0.f;
            if (tt < TM1) {
                bf16x8 xw = *(const bf16x8*)(xwp + (size_t)j*512);
                #pragma unroll
                for (int i=0;i<8;i++) p += w2r[i]*fast_tanh(dr[i] + (float)xw[i]);
            }
            s_part[tt*PSTR + lane] = p;
        }
    }
    __syncthreads();
    // ---- batched cross-lane reduce: thread -> (tt = tid>>3, g = tid&7) ----
    {
        int tt = tid >> 3, g = tid & 7;
        const float4* pp = (const float4*)(s_part + tt*PSTR + g*8);
        float4 u0 = pp[0], u1 = pp[1];
        float r = u0.x+u0.y+u0.z+u0.w + u1.x+u1.y+u1.z+u1.w;
        r += __shfl_xor(r, 1, 64);
        r += __shfl_xor(r, 2, 64);
        r += __shfl_xor(r, 4, 64);
        if (g == 0) s_sc[tt] = r;
    }
    __syncthreads();
    // ---- softmax over 63 + y via XF dot (wave 0); no max pass (|s| <= sum|W2| ~ 19) ----
    if (wave == 0) {
        float e = (lane < TM1) ? __expf(s_sc[lane]) : 0.f;
        float sum = e;
        #pragma unroll
        for (int o=32;o;o>>=1) sum += __shfl_xor(sum,o,64);
        float beta = e*fast_rcp(sum);      // lane 63 -> 0
        if (t == 62) beta_out[b*64 + lane] = beta;
        float yp = (lane < TM1) ? beta*XF[(size_t)b*TM1 + lane] : 0.f;
        #pragma unroll
        for (int o=32;o;o>>=1) yp += __shfl_xor(yp,o,64);
        if (lane == 0)
            s_y = yp + fcW[512]*y_prev[(size_t)b*TM1 + t] + fcb[0];
    }
    __syncthreads();
    float yv = s_y;
    // ---- gates + state update: k = tid (operands preloaded at top) ----
    {
        int k = tid;
        float gi = pg_i + yv*wi_i + bs_i;
        float gf = pg_f + yv*wi_f + bs_f;
        float gg = pg_g + yv*wi_g + bs_g;
        float go = pg_o + yv*wi_o + bs_o;
        size_t sk = (size_t)b*512 + k;
        float cn = fast_sigmoid(gf)*c_old + fast_sigmoid(gi)*fast_tanh(gg);
        float dn = fast_sigmoid(go)*fast_tanh(cn);
        c_f32[sk] = cn; d_f32[sk] = dn;
        dc_bf16[(size_t)b*1024 + k]       = (__bf16)dn;
        dc_bf16[(size_t)b*1024 + 512 + k] = (__bf16)cn;
    }
}

// ---------------- finish: ctx_last from beta(62) + heads ----------------
// out[0:512]=beta, [512:1024]=sigma, [1024:1536]=gamma
__global__ __launch_bounds__(512) void k_finish(
    const float* __restrict__ beta62, const __bf16* __restrict__ Xbf,
    const float* __restrict__ d_f32,
    const float* __restrict__ bW, const float* __restrict__ bb,
    const float* __restrict__ sW, const float* __restrict__ sb,
    const float* __restrict__ gW, const float* __restrict__ gb,
    float* __restrict__ out)
{
    int b = blockIdx.x;
    int tid = threadIdx.x, lane = tid & 63, wave = tid >> 6;
    __shared__ float s_beta[64];
    __shared__ float s_red[3][8];
    if (tid < 64) s_beta[tid] = beta62[b*64 + tid];
    __syncthreads();
    // ctx[e=tid] = sum_t beta[t] X[b,t,e]  (coalesced 2B loads, 63 independent)
    float ctxv = 0.f;
    {
        const __bf16* xp = Xbf + (size_t)b*TM1*512 + tid;
        #pragma unroll
        for (int tt = 0; tt < TM1; ++tt)
            ctxv += s_beta[tt]*(float)xp[(size_t)tt*512];
    }
    float dv = d_f32[(size_t)b*512 + tid];
    float pb = bW[tid]*dv + bW[512+tid]*ctxv;
    float ps = sW[tid]*dv + sW[512+tid]*ctxv;
    float pg = gW[tid]*dv + gW[512+tid]*ctxv;
    #pragma unroll
    for (int o=32;o;o>>=1) {
        pb += __shfl_xor(pb,o,64); ps += __shfl_xor(ps,o,64); pg += __shfl_xor(pg,o,64);
    }
    if (lane==0) { s_red[0][wave]=pb; s_red[1][wave]=ps; s_red[2][wave]=pg; }
    __syncthreads();
    if (tid==0) {
        float sb_=0,ss_=0,sg_=0;
        #pragma unroll
        for (int w=0;w<8;w++){ sb_+=s_red[0][w]; ss_+=s_red[1][w]; sg_+=s_red[2][w]; }
        out[b]        = sb_ + bb[0];
        out[512 + b]  = ss_ + sb[0];
        out[1024 + b] = sg_ + gb[0];
    }
}

extern "C" void kernel_launch(void* const* d_in, const int* in_sizes, int n_in,
                              void* d_out, int out_size, void* d_ws, size_t ws_size,
                              hipStream_t stream) {
    const float* X      = (const float*)d_in[0];
    const float* y_prev = (const float*)d_in[1];
    const float* W1     = (const float*)d_in[2];
    const float* b1     = (const float*)d_in[3];
    const float* W2     = (const float*)d_in[4];
    // d_in[5] = attn_b2 (softmax-invariant constant shift, skipped)
    const float* fcW    = (const float*)d_in[6];
    const float* fcb    = (const float*)d_in[7];
    const float* W_ih   = (const float*)d_in[8];
    const float* W_hh_f = (const float*)d_in[9];
    const float* b_ih   = (const float*)d_in[10];
    const float* b_hh   = (const float*)d_in[11];
    const float* betaW  = (const float*)d_in[12];
    const float* betab  = (const float*)d_in[13];
    const float* gammaW = (const float*)d_in[14];
    const float* gammab = (const float*)d_in[15];
    const float* sigmaW = (const float*)d_in[16];
    const float* sigmab = (const float*)d_in[17];
    float* out = (float*)d_out;

    size_t off = 0;
    char* ws = (char*)d_ws;
    auto alloc = [&](size_t bytes) { void* p = ws + off; off += (bytes + 255) & ~(size_t)255; return p; };
    __bf16* XWb  = (__bf16*)alloc((size_t)Bn*TM1*512*2);
    __bf16* Xbf  = (__bf16*)alloc((size_t)Bn*TM1*512*2);
    __bf16* Wdc  = (__bf16*)alloc((size_t)512*1024*2);
    __bf16* W1x  = (__bf16*)alloc((size_t)512*512*2);
    __bf16* Whh  = (__bf16*)alloc((size_t)2048*512*2);
    __bf16* dcb  = (__bf16*)alloc((size_t)Bn*1024*2);
    float*  cf   = (float*)alloc((size_t)Bn*512*4);
    float*  df   = (float*)alloc((size_t)Bn*512*4);
    float*  dcWp = (float*)alloc((size_t)4*512*512*4);
    float*  dWhhp= (float*)alloc((size_t)2*512*2048*4);
    float*  bsum = (float*)alloc((size_t)2048*4);
    float*  XF   = (float*)alloc((size_t)Bn*TM1*4);
    float*  b62  = (float*)alloc((size_t)Bn*64*4);

    hipMemsetAsync(dcb, 0, (size_t)Bn*1024*2, stream);
    hipMemsetAsync(cf,  0, (size_t)Bn*512*4, stream);

    k_prep_weights<<<512, 256, 0, stream>>>(W1, W_hh_f, b_ih, b_hh, Wdc, W1x, Whh, bsum);
    int nx = Bn*TM1*512;
    k_conv_x<<<(nx/4 + 255)/256, 256, 0, stream>>>(X, Xbf, nx);
    k_xf<<<(Bn*TM1 + 31)/32, 256, 0, stream>>>(Xbf, fcW, XF);
    k_gemm_xw<<<(Bn*TM1/64)*8, 256, 0, stream>>>(Xbf, W1x, b1, XWb);

    for (int t = 0; t < TM1; ++t) {
        k_step_gemm<<<768, 256, 0, stream>>>(dcb, Wdc, Whh, dcWp, dWhhp);
        k_step_fused<<<Bn, 512, 0, stream>>>(t, dcWp, dWhhp, XWb, XF, y_prev, W2,
                                             fcW, fcb, W_ih, bsum,
                                             cf, df, dcb, b62);
    }
    k_finish<<<Bn, 512, 0, stream>>>(b62, Xbf, df,
                                     betaW, betab, sigmaW, sigmab, gammaW, gammab, out);
}

// Round 16
// 1169.311 us; speedup vs baseline: 5.5732x; 1.1002x over previous
//
#include <hip/hip_runtime.h>

typedef __bf16 bf16x8 __attribute__((ext_vector_type(8)));
typedef float  f32x4  __attribute__((ext_vector_type(4)));

#define Bn  512
#define TM1 63

__device__ __forceinline__ float fast_rcp(float x){ return __builtin_amdgcn_rcpf(x); }
__device__ __forceinline__ float fast_tanh(float x){
    float e = __expf(2.0f*x);
    return 1.0f - 2.0f*fast_rcp(e + 1.0f);
}
__device__ __forceinline__ float fast_sigmoid(float x){
    return fast_rcp(1.0f + __expf(-x));
}

// async global->LDS, 16B per lane; lds ptr must be wave-uniform (HW adds lane*16)
__device__ __forceinline__ void gll16(const __bf16* g, __bf16* l) {
    __builtin_amdgcn_global_load_lds(
        (const __attribute__((address_space(1))) unsigned int*)(g),
        (__attribute__((address_space(3))) unsigned int*)(l),
        16, 0, 0);
}

// ---------------- setup kernels ----------------

__global__ __launch_bounds__(256) void k_prep_weights(
    const float* __restrict__ W1, const float* __restrict__ Whh_f,
    const float* __restrict__ b_ih, const float* __restrict__ b_hh,
    __bf16* __restrict__ Wdc, __bf16* __restrict__ W1x, __bf16* __restrict__ Whh,
    float* __restrict__ bsum)
{
    int i = blockIdx.x*256 + threadIdx.x;
    int n = gridDim.x*256;
    for (int idx = i; idx < 512*1024; idx += n) {
        int f = idx >> 10, k = idx & 1023;
        Wdc[idx] = (__bf16)W1[f*1536 + k];
    }
    for (int idx = i; idx < 512*512; idx += n) {
        int f = idx >> 9, k = idx & 511;
        W1x[idx] = (__bf16)W1[f*1536 + 1024 + k];
    }
    for (int idx = i; idx < 2048*512; idx += n) {
        Whh[idx] = (__bf16)Whh_f[idx];
    }
    for (int idx = i; idx < 2048; idx += n) {
        bsum[idx] = b_ih[idx] + b_hh[idx];
    }
}

__global__ __launch_bounds__(256) void k_conv_x(const float* __restrict__ X, __bf16* __restrict__ Xb, int n)
{
    int idx = (blockIdx.x*256 + threadIdx.x)*4;
    if (idx < n) {
        float4 v = *(const float4*)(X + idx);
        Xb[idx+0] = (__bf16)v.x; Xb[idx+1] = (__bf16)v.y;
        Xb[idx+2] = (__bf16)v.z; Xb[idx+3] = (__bf16)v.w;
    }
}

// XF[m] = sum_e Xbf[m,e]*fcW[e]
__global__ __launch_bounds__(256) void k_xf(
    const __bf16* __restrict__ Xbf, const float* __restrict__ fcW, float* __restrict__ XF)
{
    int lane = threadIdx.x & 63, wave = threadIdx.x >> 6;
    float fcr[8];
    {
        const float4* fp = (const float4*)(fcW + lane*8);
        float4 f0 = fp[0], f1 = fp[1];
        fcr[0]=f0.x; fcr[1]=f0.y; fcr[2]=f0.z; fcr[3]=f0.w;
        fcr[4]=f1.x; fcr[5]=f1.y; fcr[6]=f1.z; fcr[7]=f1.w;
    }
    int row0 = (blockIdx.x*4 + wave)*8;
    #pragma unroll
    for (int j = 0; j < 8; ++j) {
        int row = row0 + j;
        if (row >= Bn*TM1) break;
        bf16x8 x = *(const bf16x8*)(Xbf + (size_t)row*512 + lane*8);
        float p = 0.f;
        #pragma unroll
        for (int i=0;i<8;i++) p += fcr[i]*(float)x[i];
        #pragma unroll
        for (int o=32;o;o>>=1) p += __shfl_xor(p,o,64);
        if (lane==0) XF[row] = p;
    }
}

// ---------------- LDS-staged 64x64-tile GEMM body (XOR-swizzled) ----------------
// C[row,col] = sum_k A[row,k]*B[col,k]; 256 threads, 4 waves, 32x32/wave.
// BK=64, double-buffered LDS, global_load_lds staging, 1 barrier/K-step.
// Swizzle (both sides, rule #21): LDS 16B-chunk j of row r holds global chunk j^(r&7).
template <int ADDBIAS>
__device__ __forceinline__ void gemm_tile_lds(
    const __bf16* __restrict__ A, const __bf16* __restrict__ Bm,
    const float* __restrict__ bias, void* __restrict__ C, int as_bf16,
    int row0, int col0, int K, int lda, int ldb, int ldc,
    __bf16* sA, __bf16* sB)   // each 2*4096 elems
{
    int lane = threadIdx.x & 63, wave = threadIdx.x >> 6;
    int wr = wave >> 1, wc = wave & 1;
    int l15 = lane & 15, l4 = lane >> 4;
    int lr = lane >> 3;                      // row-in-chunk 0..7
    int lcs = ((lane & 7) ^ lr) * 8;         // inverse-swizzled source column (elements)

    auto stage = [&](int buf, int kt) {
        int k0 = kt*64;
        #pragma unroll
        for (int j = 0; j < 2; ++j) {
            int c = wave*2 + j;          // chunk 0..7, rows [c*8, c*8+8)
            int grow = c*8 + lr;
            gll16(A  + (size_t)(row0+grow)*lda + k0 + lcs, sA + buf*4096 + c*512);
            gll16(Bm + (size_t)(col0+grow)*ldb + k0 + lcs, sB + buf*4096 + c*512);
        }
    };

    int NT = K >> 6;
    stage(0, 0);
    f32x4 acc[2][2] = {};
    int s7 = l15 & 7;
    const __bf16* aRow = sA + (wr*32 + l15)*64;
    const __bf16* bRow = sB + (wc*32 + l15)*64;
    for (int kt = 0; kt < NT; ++kt) {
        int buf = kt & 1;
        asm volatile("s_waitcnt vmcnt(0)");
        __syncthreads();
        if (kt + 1 < NT) stage(buf ^ 1, kt + 1);
        #pragma unroll
        for (int kk = 0; kk < 2; ++kk) {
            int ch = ((l4 + kk*4) ^ s7) * 8;
            bf16x8 a0 = *(const bf16x8*)(aRow + buf*4096 + ch);
            bf16x8 a1 = *(const bf16x8*)(aRow + buf*4096 + 16*64 + ch);
            bf16x8 b0 = *(const bf16x8*)(bRow + buf*4096 + ch);
            bf16x8 b1 = *(const bf16x8*)(bRow + buf*4096 + 16*64 + ch);
            acc[0][0] = __builtin_amdgcn_mfma_f32_16x16x32_bf16(a0,b0,acc[0][0],0,0,0);
            acc[0][1] = __builtin_amdgcn_mfma_f32_16x16x32_bf16(a0,b1,acc[0][1],0,0,0);
            acc[1][0] = __builtin_amdgcn_mfma_f32_16x16x32_bf16(a1,b0,acc[1][0],0,0,0);
            acc[1][1] = __builtin_amdgcn_mfma_f32_16x16x32_bf16(a1,b1,acc[1][1],0,0,0);
        }
    }
    int row_a = row0 + wr*32;
    int col_b = col0 + wc*32;
    #pragma unroll
    for (int mi=0; mi<2; mi++)
    #pragma unroll
    for (int ni=0; ni<2; ni++) {
        int r0 = row_a + mi*16 + l4*4;
        int c0 = col_b + ni*16 + l15;
        float bv = ADDBIAS ? bias[c0] : 0.f;
        if (as_bf16) {
            __bf16* Cb = (__bf16*)C;
            #pragma unroll
            for (int r=0; r<4; r++)
                Cb[(size_t)(r0+r)*ldc + c0] = (__bf16)(acc[mi][ni][r] + bv);
        } else {
            float* Cf = (float*)C;
            #pragma unroll
            for (int r=0; r<4; r++)
                Cf[(size_t)(r0+r)*ldc + c0] = acc[mi][ni][r];
        }
    }
}

// XW[m,f] = sum_e Xbf[m,e]*W1x[f,e] + b1[f]; M=32256,N=512,K=512
__global__ __launch_bounds__(256) void k_gemm_xw(
    const __bf16* __restrict__ A, const __bf16* __restrict__ Bm,
    const float* __restrict__ bias, __bf16* __restrict__ C)
{
    __shared__ __bf16 sA[2*4096], sB[2*4096];
    // XCD-chunked bijective swizzle: 4032 blocks = 8 XCDs x 504
    int orig = (blockIdx.x & 7)*504 + (blockIdx.x >> 3);
    int tm = orig >> 3, tn = orig & 7;
    gemm_tile_lds<1>(A, Bm, bias, C, 1, tm*64, tn*64, 512, 512, 512, 512, sA, sB);
}

// 768 UNIFORM K=256 jobs = exactly 3 blocks/CU.
// R15 change: split-K intermediates stored BF16 (halves phase-A write traffic
// and fused-kernel read traffic; partials ~0.5 magnitude, bf16 quant ~0.4%).
// blocks 0..255:  dcWp[kh][512][512], kh=blk&3   (dcW K=1024 in 4 quarters)
// blocks 256..767: dWhhp[kh][512][2048], kh=b2&1 (dWhh K=512 in 2 halves)
__global__ __launch_bounds__(256) void k_step_gemm(
    const __bf16* __restrict__ dc, const __bf16* __restrict__ Wdc,
    const __bf16* __restrict__ Whh, __bf16* __restrict__ dcWp, __bf16* __restrict__ dWhhp)
{
    __shared__ __bf16 sA[2*4096], sB[2*4096];
    int blk = blockIdx.x;
    if (blk < 256) {
        int kh = blk & 3, tt = blk >> 2;
        int tm = tt >> 3, tn = tt & 7;
        gemm_tile_lds<0>(dc + kh*256, Wdc + kh*256, nullptr,
                         dcWp + (size_t)kh*512*512, 1,
                         tm*64, tn*64, 256, 1024, 1024, 512, sA, sB);
    } else {
        int b2 = blk - 256;
        int kh = b2 & 1, tt = b2 >> 1;
        int tm = tt >> 5, tn = tt & 31;
        gemm_tile_lds<0>(dc + kh*256, Whh + kh*256, nullptr,
                         dWhhp + (size_t)kh*512*2048, 1,
                         tm*64, tn*64, 256, 1024, 512, 2048, sA, sB);
    }
}

// ---------------- per-step fused kernel ----------------

// one block (512 threads) per batch row; no ctx phase (XF trick)
#define PSTR 76   // s_part row stride (floats)
__global__ __launch_bounds__(512) void k_step_fused(
    int t,
    const __bf16* __restrict__ dcWp, const __bf16* __restrict__ dWhhp,
    const __bf16* __restrict__ XWb, const float* __restrict__ XF,
    const float* __restrict__ y_prev, const float* __restrict__ W2,
    const float* __restrict__ fcW, const float* __restrict__ fcb,
    const float* __restrict__ W_ih, const float* __restrict__ bsum,
    float* __restrict__ c_f32, float* __restrict__ d_f32,
    __bf16* __restrict__ dc_bf16, float* __restrict__ beta_out)
{
    int b = blockIdx.x;
    int tid = threadIdx.x, lane = tid & 63, wave = tid >> 6;
    __shared__ float s_part[64*PSTR];
    __shared__ float s_sc[64];
    __shared__ float s_y;

    // gate-phase operands hoisted (independent of scores/softmax; latency hides
    // under the tanh phase). dWhh = sum of 2 split-K halves (bf16).
    size_t gb = (size_t)b*2048 + tid;
    const __bf16* dW0 = dWhhp;
    const __bf16* dW1 = dWhhp + (size_t)512*2048;
    float pg_i = (float)dW0[gb]        + (float)dW1[gb];
    float pg_f = (float)dW0[gb + 512]  + (float)dW1[gb + 512];
    float pg_g = (float)dW0[gb + 1024] + (float)dW1[gb + 1024];
    float pg_o = (float)dW0[gb + 1536] + (float)dW1[gb + 1536];
    float wi_i = W_ih[tid];
    float wi_f = W_ih[512 + tid];
    float wi_g = W_ih[1024 + tid];
    float wi_o = W_ih[1536 + tid];
    float bs_i = bsum[tid];
    float bs_f = bsum[512 + tid];
    float bs_g = bsum[1024 + tid];
    float bs_o = bsum[1536 + tid];
    float c_old = c_f32[(size_t)b*512 + tid];

    // per-lane W2 / dcW slices in registers; dcW = sum of the 4 split-K quarters (bf16)
    float w2r[8], dr[8];
    {
        const float4* w2p = (const float4*)(W2 + lane*8);
        float4 w0 = w2p[0], w1 = w2p[1];
        w2r[0]=w0.x; w2r[1]=w0.y; w2r[2]=w0.z; w2r[3]=w0.w;
        w2r[4]=w1.x; w2r[5]=w1.y; w2r[6]=w1.z; w2r[7]=w1.w;
        #pragma unroll
        for (int i=0;i<8;i++) dr[i] = 0.f;
        #pragma unroll
        for (int q=0;q<4;q++) {
            bf16x8 a = *(const bf16x8*)(dcWp + (size_t)q*512*512 + (size_t)b*512 + lane*8);
            #pragma unroll
            for (int i=0;i<8;i++) dr[i] += (float)a[i];
        }
    }
    // ---- scores: wave w -> t in {w*8..w*8+7}, lane = f-slice (coalesced 1KB/row) ----
    {
        const __bf16* xwp = XWb + ((size_t)b*TM1 + wave*8)*512 + lane*8;
        #pragma unroll
        for (int j = 0; j < 8; ++j) {
            int tt = wave*8 + j;
            float p = 0.f;
            if (tt < TM1) {
                bf16x8 xw = *(const bf16x8*)(xwp + (size_t)j*512);
                #pragma unroll
                for (int i=0;i<8;i++) p += w2r[i]*fast_tanh(dr[i] + (float)xw[i]);
            }
            s_part[tt*PSTR + lane] = p;
        }
    }
    __syncthreads();
    // ---- batched cross-lane reduce: thread -> (tt = tid>>3, g = tid&7) ----
    {
        int tt = tid >> 3, g = tid & 7;
        const float4* pp = (const float4*)(s_part + tt*PSTR + g*8);
        float4 u0 = pp[0], u1 = pp[1];
        float r = u0.x+u0.y+u0.z+u0.w + u1.x+u1.y+u1.z+u1.w;
        r += __shfl_xor(r, 1, 64);
        r += __shfl_xor(r, 2, 64);
        r += __shfl_xor(r, 4, 64);
        if (g == 0) s_sc[tt] = r;
    }
    __syncthreads();
    // ---- softmax over 63 + y via XF dot (wave 0); no max pass (|s| <= sum|W2| ~ 19) ----
    if (wave == 0) {
        float e = (lane < TM1) ? __expf(s_sc[lane]) : 0.f;
        float sum = e;
        #pragma unroll
        for (int o=32;o;o>>=1) sum += __shfl_xor(sum,o,64);
        float beta = e*fast_rcp(sum);      // lane 63 -> 0
        if (t == 62) beta_out[b*64 + lane] = beta;
        float yp = (lane < TM1) ? beta*XF[(size_t)b*TM1 + lane] : 0.f;
        #pragma unroll
        for (int o=32;o;o>>=1) yp += __shfl_xor(yp,o,64);
        if (lane == 0)
            s_y = yp + fcW[512]*y_prev[(size_t)b*TM1 + t] + fcb[0];
    }
    __syncthreads();
    float yv = s_y;
    // ---- gates + state update: k = tid (operands preloaded at top) ----
    {
        int k = tid;
        float gi = pg_i + yv*wi_i + bs_i;
        float gf = pg_f + yv*wi_f + bs_f;
        float gg = pg_g + yv*wi_g + bs_g;
        float go = pg_o + yv*wi_o + bs_o;
        size_t sk = (size_t)b*512 + k;
        float cn = fast_sigmoid(gf)*c_old + fast_sigmoid(gi)*fast_tanh(gg);
        float dn = fast_sigmoid(go)*fast_tanh(cn);
        c_f32[sk] = cn; d_f32[sk] = dn;
        dc_bf16[(size_t)b*1024 + k]       = (__bf16)dn;
        dc_bf16[(size_t)b*1024 + 512 + k] = (__bf16)cn;
    }
}

// ---------------- finish: ctx_last from beta(62) + heads ----------------
// out[0:512]=beta, [512:1024]=sigma, [1024:1536]=gamma
__global__ __launch_bounds__(512) void k_finish(
    const float* __restrict__ beta62, const __bf16* __restrict__ Xbf,
    const float* __restrict__ d_f32,
    const float* __restrict__ bW, const float* __restrict__ bb,
    const float* __restrict__ sW, const float* __restrict__ sb,
    const float* __restrict__ gW, const float* __restrict__ gb,
    float* __restrict__ out)
{
    int b = blockIdx.x;
    int tid = threadIdx.x, lane = tid & 63, wave = tid >> 6;
    __shared__ float s_beta[64];
    __shared__ float s_red[3][8];
    if (tid < 64) s_beta[tid] = beta62[b*64 + tid];
    __syncthreads();
    // ctx[e=tid] = sum_t beta[t] X[b,t,e]  (coalesced 2B loads, 63 independent)
    float ctxv = 0.f;
    {
        const __bf16* xp = Xbf + (size_t)b*TM1*512 + tid;
        #pragma unroll
        for (int tt = 0; tt < TM1; ++tt)
            ctxv += s_beta[tt]*(float)xp[(size_t)tt*512];
    }
    float dv = d_f32[(size_t)b*512 + tid];
    float pb = bW[tid]*dv + bW[512+tid]*ctxv;
    float ps = sW[tid]*dv + sW[512+tid]*ctxv;
    float pg = gW[tid]*dv + gW[512+tid]*ctxv;
    #pragma unroll
    for (int o=32;o;o>>=1) {
        pb += __shfl_xor(pb,o,64); ps += __shfl_xor(ps,o,64); pg += __shfl_xor(pg,o,64);
    }
    if (lane==0) { s_red[0][wave]=pb; s_red[1][wave]=ps; s_red[2][wave]=pg; }
    __syncthreads();
    if (tid==0) {
        float sb_=0,ss_=0,sg_=0;
        #pragma unroll
        for (int w=0;w<8;w++){ sb_+=s_red[0][w]; ss_+=s_red[1][w]; sg_+=s_red[2][w]; }
        out[b]        = sb_ + bb[0];
        out[512 + b]  = ss_ + sb[0];
        out[1024 + b] = sg_ + gb[0];
    }
}

extern "C" void kernel_launch(void* const* d_in, const int* in_sizes, int n_in,
                              void* d_out, int out_size, void* d_ws, size_t ws_size,
                              hipStream_t stream) {
    const float* X      = (const float*)d_in[0];
    const float* y_prev = (const float*)d_in[1];
    const float* W1     = (const float*)d_in[2];
    const float* b1     = (const float*)d_in[3];
    const float* W2     = (const float*)d_in[4];
    // d_in[5] = attn_b2 (softmax-invariant constant shift, skipped)
    const float* fcW    = (const float*)d_in[6];
    const float* fcb    = (const float*)d_in[7];
    const float* W_ih   = (const float*)d_in[8];
    const float* W_hh_f = (const float*)d_in[9];
    const float* b_ih   = (const float*)d_in[10];
    const float* b_hh   = (const float*)d_in[11];
    const float* betaW  = (const float*)d_in[12];
    const float* betab  = (const float*)d_in[13];
    const float* gammaW = (const float*)d_in[14];
    const float* gammab = (const float*)d_in[15];
    const float* sigmaW = (const float*)d_in[16];
    const float* sigmab = (const float*)d_in[17];
    float* out = (float*)d_out;

    size_t off = 0;
    char* ws = (char*)d_ws;
    auto alloc = [&](size_t bytes) { void* p = ws + off; off += (bytes + 255) & ~(size_t)255; return p; };
    __bf16* XWb  = (__bf16*)alloc((size_t)Bn*TM1*512*2);
    __bf16* Xbf  = (__bf16*)alloc((size_t)Bn*TM1*512*2);
    __bf16* Wdc  = (__bf16*)alloc((size_t)512*1024*2);
    __bf16* W1x  = (__bf16*)alloc((size_t)512*512*2);
    __bf16* Whh  = (__bf16*)alloc((size_t)2048*512*2);
    __bf16* dcb  = (__bf16*)alloc((size_t)Bn*1024*2);
    float*  cf   = (float*)alloc((size_t)Bn*512*4);
    float*  df   = (float*)alloc((size_t)Bn*512*4);
    __bf16* dcWp = (__bf16*)alloc((size_t)4*512*512*2);
    __bf16* dWhhp= (__bf16*)alloc((size_t)2*512*2048*2);
    float*  bsum = (float*)alloc((size_t)2048*4);
    float*  XF   = (float*)alloc((size_t)Bn*TM1*4);
    float*  b62  = (float*)alloc((size_t)Bn*64*4);

    hipMemsetAsync(dcb, 0, (size_t)Bn*1024*2, stream);
    hipMemsetAsync(cf,  0, (size_t)Bn*512*4, stream);

    k_prep_weights<<<512, 256, 0, stream>>>(W1, W_hh_f, b_ih, b_hh, Wdc, W1x, Whh, bsum);
    int nx = Bn*TM1*512;
    k_conv_x<<<(nx/4 + 255)/256, 256, 0, stream>>>(X, Xbf, nx);
    k_xf<<<(Bn*TM1 + 31)/32, 256, 0, stream>>>(Xbf, fcW, XF);
    k_gemm_xw<<<(Bn*TM1/64)*8, 256, 0, stream>>>(Xbf, W1x, b1, XWb);

    for (int t = 0; t < TM1; ++t) {
        k_step_gemm<<<768, 256, 0, stream>>>(dcb, Wdc, Whh, dcWp, dWhhp);
        k_step_fused<<<Bn, 512, 0, stream>>>(t, dcWp, dWhhp, XWb, XF, y_prev, W2,
                                             fcW, fcb, W_ih, bsum,
                                             cf, df, dcb, b62);
    }
    k_finish<<<Bn, 512, 0, stream>>>(b62, Xbf, df,
                                     betaW, betab, sigmaW, sigmab, gammaW, gammab, out);
}

// Round 17
// 1162.024 us; speedup vs baseline: 5.6082x; 1.0063x over previous
//
#include <hip/hip_runtime.h>

typedef __bf16 bf16x8 __attribute__((ext_vector_type(8)));
typedef float  f32x4  __attribute__((ext_vector_type(4)));

#define Bn  512
#define TM1 63

__device__ __forceinline__ float fast_rcp(float x){ return __builtin_amdgcn_rcpf(x); }
__device__ __forceinline__ float fast_tanh(float x){
    float e = __expf(2.0f*x);
    return 1.0f - 2.0f*fast_rcp(e + 1.0f);
}
__device__ __forceinline__ float fast_sigmoid(float x){
    return fast_rcp(1.0f + __expf(-x));
}

// async global->LDS, 16B per lane; lds ptr must be wave-uniform (HW adds lane*16)
__device__ __forceinline__ void gll16(const __bf16* g, __bf16* l) {
    __builtin_amdgcn_global_load_lds(
        (const __attribute__((address_space(1))) unsigned int*)(g),
        (__attribute__((address_space(3))) unsigned int*)(l),
        16, 0, 0);
}

// ---------------- setup kernels ----------------

__global__ __launch_bounds__(256) void k_prep_weights(
    const float* __restrict__ W1, const float* __restrict__ Whh_f,
    const float* __restrict__ b_ih, const float* __restrict__ b_hh,
    __bf16* __restrict__ Wdc, __bf16* __restrict__ W1x, __bf16* __restrict__ Whh,
    float* __restrict__ bsum)
{
    int i = blockIdx.x*256 + threadIdx.x;
    int n = gridDim.x*256;
    for (int idx = i; idx < 512*1024; idx += n) {
        int f = idx >> 10, k = idx & 1023;
        Wdc[idx] = (__bf16)W1[f*1536 + k];
    }
    for (int idx = i; idx < 512*512; idx += n) {
        int f = idx >> 9, k = idx & 511;
        W1x[idx] = (__bf16)W1[f*1536 + 1024 + k];
    }
    for (int idx = i; idx < 2048*512; idx += n) {
        Whh[idx] = (__bf16)Whh_f[idx];
    }
    for (int idx = i; idx < 2048; idx += n) {
        bsum[idx] = b_ih[idx] + b_hh[idx];
    }
}

// Fused conv + XF (R16): one pass over X — convert f32->bf16 AND dot with fcW.
// wave-per-row; XF[m] = sum_e X[m,e]*fcW[e]
__global__ __launch_bounds__(256) void k_conv_xf(
    const float* __restrict__ X, const float* __restrict__ fcW,
    __bf16* __restrict__ Xb, float* __restrict__ XF)
{
    int lane = threadIdx.x & 63, wave = threadIdx.x >> 6;
    float fcr[8];
    {
        const float4* fp = (const float4*)(fcW + lane*8);
        float4 f0 = fp[0], f1 = fp[1];
        fcr[0]=f0.x; fcr[1]=f0.y; fcr[2]=f0.z; fcr[3]=f0.w;
        fcr[4]=f1.x; fcr[5]=f1.y; fcr[6]=f1.z; fcr[7]=f1.w;
    }
    int row = blockIdx.x*4 + wave;
    if (row >= Bn*TM1) return;
    const float4* xp = (const float4*)(X + (size_t)row*512 + lane*8);
    float4 v0 = xp[0], v1 = xp[1];
    bf16x8 xb;
    xb[0]=(__bf16)v0.x; xb[1]=(__bf16)v0.y; xb[2]=(__bf16)v0.z; xb[3]=(__bf16)v0.w;
    xb[4]=(__bf16)v1.x; xb[5]=(__bf16)v1.y; xb[6]=(__bf16)v1.z; xb[7]=(__bf16)v1.w;
    *(bf16x8*)(Xb + (size_t)row*512 + lane*8) = xb;
    float p = fcr[0]*v0.x + fcr[1]*v0.y + fcr[2]*v0.z + fcr[3]*v0.w
            + fcr[4]*v1.x + fcr[5]*v1.y + fcr[6]*v1.z + fcr[7]*v1.w;
    #pragma unroll
    for (int o=32;o;o>>=1) p += __shfl_xor(p,o,64);
    if (lane==0) XF[row] = p;
}

// ---------------- LDS-staged 64x64-tile GEMM body (XOR-swizzled) ----------------
// C[row,col] = sum_k A[row,k]*B[col,k]; 256 threads, 4 waves, 32x32/wave.
template <int ADDBIAS>
__device__ __forceinline__ void gemm_tile_lds(
    const __bf16* __restrict__ A, const __bf16* __restrict__ Bm,
    const float* __restrict__ bias, void* __restrict__ C, int as_bf16,
    int row0, int col0, int K, int lda, int ldb, int ldc,
    __bf16* sA, __bf16* sB)   // each 2*4096 elems
{
    int lane = threadIdx.x & 63, wave = threadIdx.x >> 6;
    int wr = wave >> 1, wc = wave & 1;
    int l15 = lane & 15, l4 = lane >> 4;
    int lr = lane >> 3;                      // row-in-chunk 0..7
    int lcs = ((lane & 7) ^ lr) * 8;         // inverse-swizzled source column (elements)

    auto stage = [&](int buf, int kt) {
        int k0 = kt*64;
        #pragma unroll
        for (int j = 0; j < 2; ++j) {
            int c = wave*2 + j;          // chunk 0..7, rows [c*8, c*8+8)
            int grow = c*8 + lr;
            gll16(A  + (size_t)(row0+grow)*lda + k0 + lcs, sA + buf*4096 + c*512);
            gll16(Bm + (size_t)(col0+grow)*ldb + k0 + lcs, sB + buf*4096 + c*512);
        }
    };

    int NT = K >> 6;
    stage(0, 0);
    f32x4 acc[2][2] = {};
    int s7 = l15 & 7;
    const __bf16* aRow = sA + (wr*32 + l15)*64;
    const __bf16* bRow = sB + (wc*32 + l15)*64;
    for (int kt = 0; kt < NT; ++kt) {
        int buf = kt & 1;
        asm volatile("s_waitcnt vmcnt(0)");
        __syncthreads();
        if (kt + 1 < NT) stage(buf ^ 1, kt + 1);
        #pragma unroll
        for (int kk = 0; kk < 2; ++kk) {
            int ch = ((l4 + kk*4) ^ s7) * 8;
            bf16x8 a0 = *(const bf16x8*)(aRow + buf*4096 + ch);
            bf16x8 a1 = *(const bf16x8*)(aRow + buf*4096 + 16*64 + ch);
            bf16x8 b0 = *(const bf16x8*)(bRow + buf*4096 + ch);
            bf16x8 b1 = *(const bf16x8*)(bRow + buf*4096 + 16*64 + ch);
            acc[0][0] = __builtin_amdgcn_mfma_f32_16x16x32_bf16(a0,b0,acc[0][0],0,0,0);
            acc[0][1] = __builtin_amdgcn_mfma_f32_16x16x32_bf16(a0,b1,acc[0][1],0,0,0);
            acc[1][0] = __builtin_amdgcn_mfma_f32_16x16x32_bf16(a1,b0,acc[1][0],0,0,0);
            acc[1][1] = __builtin_amdgcn_mfma_f32_16x16x32_bf16(a1,b1,acc[1][1],0,0,0);
        }
    }
    int row_a = row0 + wr*32;
    int col_b = col0 + wc*32;
    #pragma unroll
    for (int mi=0; mi<2; mi++)
    #pragma unroll
    for (int ni=0; ni<2; ni++) {
        int r0 = row_a + mi*16 + l4*4;
        int c0 = col_b + ni*16 + l15;
        float bv = ADDBIAS ? bias[c0] : 0.f;
        if (as_bf16) {
            __bf16* Cb = (__bf16*)C;
            #pragma unroll
            for (int r=0; r<4; r++)
                Cb[(size_t)(r0+r)*ldc + c0] = (__bf16)(acc[mi][ni][r] + bv);
        } else {
            float* Cf = (float*)C;
            #pragma unroll
            for (int r=0; r<4; r++)
                Cf[(size_t)(r0+r)*ldc + c0] = acc[mi][ni][r];
        }
    }
}

// XW[m,f] = sum_e Xbf[m,e]*W1x[f,e] + b1[f]; M=32256,N=512,K=512.
// R16: 128x64 tile (vs 64x64) — 2x MFMA per staged byte; LDS 48KB -> 3 blocks/CU.
__global__ __launch_bounds__(256) void k_gemm_xw(
    const __bf16* __restrict__ A, const __bf16* __restrict__ Bm,
    const float* __restrict__ bias, __bf16* __restrict__ C)
{
    __shared__ __bf16 sA[2*8192];   // 128x64 per buf
    __shared__ __bf16 sB[2*4096];   // 64x64 per buf
    // XCD-chunked bijective swizzle: 2016 blocks = 8 XCDs x 252
    int orig = (blockIdx.x & 7)*252 + (blockIdx.x >> 3);
    int tm = orig >> 3, tn = orig & 7;
    int row0 = tm*128, col0 = tn*64;
    int lane = threadIdx.x & 63, wave = threadIdx.x >> 6;
    int l15 = lane & 15, l4 = lane >> 4;
    int lr = lane >> 3;
    int lcs = ((lane & 7) ^ lr) * 8;

    auto stage = [&](int buf, int kt) {
        int k0 = kt*64;
        #pragma unroll
        for (int j = 0; j < 4; ++j) {          // A: 16 chunks of 8 rows
            int c = wave*4 + j;
            int grow = c*8 + lr;
            gll16(A + (size_t)(row0+grow)*512 + k0 + lcs, sA + buf*8192 + c*512);
        }
        #pragma unroll
        for (int j = 0; j < 2; ++j) {          // B: 8 chunks of 8 rows
            int c = wave*2 + j;
            int grow = c*8 + lr;
            gll16(Bm + (size_t)(col0+grow)*512 + k0 + lcs, sB + buf*4096 + c*512);
        }
    };

    stage(0, 0);
    f32x4 acc[2][4] = {};
    int s7 = l15 & 7;
    const __bf16* aRow = sA + (wave*32 + l15)*64;   // wave owns rows wave*32..+32
    const __bf16* bRow = sB + l15*64;
    for (int kt = 0; kt < 8; ++kt) {
        int buf = kt & 1;
        asm volatile("s_waitcnt vmcnt(0)");
        __syncthreads();
        if (kt + 1 < 8) stage(buf ^ 1, kt + 1);
        #pragma unroll
        for (int kk = 0; kk < 2; ++kk) {
            int ch = ((l4 + kk*4) ^ s7) * 8;
            bf16x8 a0 = *(const bf16x8*)(aRow + buf*8192 + ch);
            bf16x8 a1 = *(const bf16x8*)(aRow + buf*8192 + 16*64 + ch);
            bf16x8 b0 = *(const bf16x8*)(bRow + buf*4096 + ch);
            bf16x8 b1 = *(const bf16x8*)(bRow + buf*4096 + 16*64 + ch);
            bf16x8 b2 = *(const bf16x8*)(bRow + buf*4096 + 32*64 + ch);
            bf16x8 b3 = *(const bf16x8*)(bRow + buf*4096 + 48*64 + ch);
            acc[0][0] = __builtin_amdgcn_mfma_f32_16x16x32_bf16(a0,b0,acc[0][0],0,0,0);
            acc[0][1] = __builtin_amdgcn_mfma_f32_16x16x32_bf16(a0,b1,acc[0][1],0,0,0);
            acc[0][2] = __builtin_amdgcn_mfma_f32_16x16x32_bf16(a0,b2,acc[0][2],0,0,0);
            acc[0][3] = __builtin_amdgcn_mfma_f32_16x16x32_bf16(a0,b3,acc[0][3],0,0,0);
            acc[1][0] = __builtin_amdgcn_mfma_f32_16x16x32_bf16(a1,b0,acc[1][0],0,0,0);
            acc[1][1] = __builtin_amdgcn_mfma_f32_16x16x32_bf16(a1,b1,acc[1][1],0,0,0);
            acc[1][2] = __builtin_amdgcn_mfma_f32_16x16x32_bf16(a1,b2,acc[1][2],0,0,0);
            acc[1][3] = __builtin_amdgcn_mfma_f32_16x16x32_bf16(a1,b3,acc[1][3],0,0,0);
        }
    }
    #pragma unroll
    for (int mi=0; mi<2; mi++)
    #pragma unroll
    for (int ni=0; ni<4; ni++) {
        int r0 = row0 + wave*32 + mi*16 + l4*4;
        int c0 = col0 + ni*16 + l15;
        float bv = bias[c0];
        #pragma unroll
        for (int r=0; r<4; r++)
            C[(size_t)(r0+r)*512 + c0] = (__bf16)(acc[mi][ni][r] + bv);
    }
}

// 768 UNIFORM K=256 jobs = exactly 3 blocks/CU; bf16 split-K intermediates.
// blocks 0..255:  dcWp[kh][512][512], kh=blk&3   (dcW K=1024 in 4 quarters)
// blocks 256..767: dWhhp[kh][512][2048], kh=b2&1 (dWhh K=512 in 2 halves)
__global__ __launch_bounds__(256) void k_step_gemm(
    const __bf16* __restrict__ dc, const __bf16* __restrict__ Wdc,
    const __bf16* __restrict__ Whh, __bf16* __restrict__ dcWp, __bf16* __restrict__ dWhhp)
{
    __shared__ __bf16 sA[2*4096], sB[2*4096];
    int blk = blockIdx.x;
    if (blk < 256) {
        int kh = blk & 3, tt = blk >> 2;
        int tm = tt >> 3, tn = tt & 7;
        gemm_tile_lds<0>(dc + kh*256, Wdc + kh*256, nullptr,
                         dcWp + (size_t)kh*512*512, 1,
                         tm*64, tn*64, 256, 1024, 1024, 512, sA, sB);
    } else {
        int b2 = blk - 256;
        int kh = b2 & 1, tt = b2 >> 1;
        int tm = tt >> 5, tn = tt & 31;
        gemm_tile_lds<0>(dc + kh*256, Whh + kh*256, nullptr,
                         dWhhp + (size_t)kh*512*2048, 1,
                         tm*64, tn*64, 256, 1024, 512, 2048, sA, sB);
    }
}

// ---------------- per-step fused kernel ----------------

// one block (512 threads) per batch row; no ctx phase (XF trick)
#define PSTR 76   // s_part row stride (floats)
__global__ __launch_bounds__(512) void k_step_fused(
    int t,
    const __bf16* __restrict__ dcWp, const __bf16* __restrict__ dWhhp,
    const __bf16* __restrict__ XWb, const float* __restrict__ XF,
    const float* __restrict__ y_prev, const float* __restrict__ W2,
    const float* __restrict__ fcW, const float* __restrict__ fcb,
    const float* __restrict__ W_ih, const float* __restrict__ bsum,
    float* __restrict__ c_f32, float* __restrict__ d_f32,
    __bf16* __restrict__ dc_bf16, float* __restrict__ beta_out)
{
    int b = blockIdx.x;
    int tid = threadIdx.x, lane = tid & 63, wave = tid >> 6;
    __shared__ float s_part[64*PSTR];
    __shared__ float s_sc[64];
    __shared__ float s_y;

    // gate-phase operands hoisted; dWhh = sum of 2 split-K halves (bf16).
    size_t gb = (size_t)b*2048 + tid;
    const __bf16* dW0 = dWhhp;
    const __bf16* dW1 = dWhhp + (size_t)512*2048;
    float pg_i = (float)dW0[gb]        + (float)dW1[gb];
    float pg_f = (float)dW0[gb + 512]  + (float)dW1[gb + 512];
    float pg_g = (float)dW0[gb + 1024] + (float)dW1[gb + 1024];
    float pg_o = (float)dW0[gb + 1536] + (float)dW1[gb + 1536];
    float wi_i = W_ih[tid];
    float wi_f = W_ih[512 + tid];
    float wi_g = W_ih[1024 + tid];
    float wi_o = W_ih[1536 + tid];
    float bs_i = bsum[tid];
    float bs_f = bsum[512 + tid];
    float bs_g = bsum[1024 + tid];
    float bs_o = bsum[1536 + tid];
    float c_old = c_f32[(size_t)b*512 + tid];

    // per-lane W2 / dcW slices in registers; dcW = sum of the 4 split-K quarters (bf16)
    float w2r[8], dr[8];
    {
        const float4* w2p = (const float4*)(W2 + lane*8);
        float4 w0 = w2p[0], w1 = w2p[1];
        w2r[0]=w0.x; w2r[1]=w0.y; w2r[2]=w0.z; w2r[3]=w0.w;
        w2r[4]=w1.x; w2r[5]=w1.y; w2r[6]=w1.z; w2r[7]=w1.w;
        #pragma unroll
        for (int i=0;i<8;i++) dr[i] = 0.f;
        #pragma unroll
        for (int q=0;q<4;q++) {
            bf16x8 a = *(const bf16x8*)(dcWp + (size_t)q*512*512 + (size_t)b*512 + lane*8);
            #pragma unroll
            for (int i=0;i<8;i++) dr[i] += (float)a[i];
        }
    }
    // ---- scores: wave w -> t in {w*8..w*8+7}, lane = f-slice (coalesced 1KB/row) ----
    {
        const __bf16* xwp = XWb + ((size_t)b*TM1 + wave*8)*512 + lane*8;
        #pragma unroll
        for (int j = 0; j < 8; ++j) {
            int tt = wave*8 + j;
            float p = 0.f;
            if (tt < TM1) {
                bf16x8 xw = *(const bf16x8*)(xwp + (size_t)j*512);
                #pragma unroll
                for (int i=0;i<8;i++) p += w2r[i]*fast_tanh(dr[i] + (float)xw[i]);
            }
            s_part[tt*PSTR + lane] = p;
        }
    }
    __syncthreads();
    // ---- batched cross-lane reduce: thread -> (tt = tid>>3, g = tid&7) ----
    {
        int tt = tid >> 3, g = tid & 7;
        const float4* pp = (const float4*)(s_part + tt*PSTR + g*8);
        float4 u0 = pp[0], u1 = pp[1];
        float r = u0.x+u0.y+u0.z+u0.w + u1.x+u1.y+u1.z+u1.w;
        r += __shfl_xor(r, 1, 64);
        r += __shfl_xor(r, 2, 64);
        r += __shfl_xor(r, 4, 64);
        if (g == 0) s_sc[tt] = r;
    }
    __syncthreads();
    // ---- softmax over 63 + y via XF dot (wave 0); no max pass (|s| <= sum|W2| ~ 19) ----
    if (wave == 0) {
        float e = (lane < TM1) ? __expf(s_sc[lane]) : 0.f;
        float sum = e;
        #pragma unroll
        for (int o=32;o;o>>=1) sum += __shfl_xor(sum,o,64);
        float beta = e*fast_rcp(sum);      // lane 63 -> 0
        if (t == 62) beta_out[b*64 + lane] = beta;
        float yp = (lane < TM1) ? beta*XF[(size_t)b*TM1 + lane] : 0.f;
        #pragma unroll
        for (int o=32;o;o>>=1) yp += __shfl_xor(yp,o,64);
        if (lane == 0)
            s_y = yp + fcW[512]*y_prev[(size_t)b*TM1 + t] + fcb[0];
    }
    __syncthreads();
    float yv = s_y;
    // ---- gates + state update: k = tid (operands preloaded at top) ----
    {
        int k = tid;
        float gi = pg_i + yv*wi_i + bs_i;
        float gf = pg_f + yv*wi_f + bs_f;
        float gg = pg_g + yv*wi_g + bs_g;
        float go = pg_o + yv*wi_o + bs_o;
        size_t sk = (size_t)b*512 + k;
        float cn = fast_sigmoid(gf)*c_old + fast_sigmoid(gi)*fast_tanh(gg);
        float dn = fast_sigmoid(go)*fast_tanh(cn);
        c_f32[sk] = cn; d_f32[sk] = dn;
        dc_bf16[(size_t)b*1024 + k]       = (__bf16)dn;
        dc_bf16[(size_t)b*1024 + 512 + k] = (__bf16)cn;
    }
}

// ---------------- finish: ctx_last from beta(62) + heads ----------------
// out[0:512]=beta, [512:1024]=sigma, [1024:1536]=gamma
__global__ __launch_bounds__(512) void k_finish(
    const float* __restrict__ beta62, const __bf16* __restrict__ Xbf,
    const float* __restrict__ d_f32,
    const float* __restrict__ bW, const float* __restrict__ bb,
    const float* __restrict__ sW, const float* __restrict__ sb,
    const float* __restrict__ gW, const float* __restrict__ gb,
    float* __restrict__ out)
{
    int b = blockIdx.x;
    int tid = threadIdx.x, lane = tid & 63, wave = tid >> 6;
    __shared__ float s_beta[64];
    __shared__ float s_red[3][8];
    if (tid < 64) s_beta[tid] = beta62[b*64 + tid];
    __syncthreads();
    // ctx[e=tid] = sum_t beta[t] X[b,t,e]  (coalesced 2B loads, 63 independent)
    float ctxv = 0.f;
    {
        const __bf16* xp = Xbf + (size_t)b*TM1*512 + tid;
        #pragma unroll
        for (int tt = 0; tt < TM1; ++tt)
            ctxv += s_beta[tt]*(float)xp[(size_t)tt*512];
    }
    float dv = d_f32[(size_t)b*512 + tid];
    float pb = bW[tid]*dv + bW[512+tid]*ctxv;
    float ps = sW[tid]*dv + sW[512+tid]*ctxv;
    float pg = gW[tid]*dv + gW[512+tid]*ctxv;
    #pragma unroll
    for (int o=32;o;o>>=1) {
        pb += __shfl_xor(pb,o,64); ps += __shfl_xor(ps,o,64); pg += __shfl_xor(pg,o,64);
    }
    if (lane==0) { s_red[0][wave]=pb; s_red[1][wave]=ps; s_red[2][wave]=pg; }
    __syncthreads();
    if (tid==0) {
        float sb_=0,ss_=0,sg_=0;
        #pragma unroll
        for (int w=0;w<8;w++){ sb_+=s_red[0][w]; ss_+=s_red[1][w]; sg_+=s_red[2][w]; }
        out[b]        = sb_ + bb[0];
        out[512 + b]  = ss_ + sb[0];
        out[1024 + b] = sg_ + gb[0];
    }
}

extern "C" void kernel_launch(void* const* d_in, const int* in_sizes, int n_in,
                              void* d_out, int out_size, void* d_ws, size_t ws_size,
                              hipStream_t stream) {
    const float* X      = (const float*)d_in[0];
    const float* y_prev = (const float*)d_in[1];
    const float* W1     = (const float*)d_in[2];
    const float* b1     = (const float*)d_in[3];
    const float* W2     = (const float*)d_in[4];
    // d_in[5] = attn_b2 (softmax-invariant constant shift, skipped)
    const float* fcW    = (const float*)d_in[6];
    const float* fcb    = (const float*)d_in[7];
    const float* W_ih   = (const float*)d_in[8];
    const float* W_hh_f = (const float*)d_in[9];
    const float* b_ih   = (const float*)d_in[10];
    const float* b_hh   = (const float*)d_in[11];
    const float* betaW  = (const float*)d_in[12];
    const float* betab  = (const float*)d_in[13];
    const float* gammaW = (const float*)d_in[14];
    const float* gammab = (const float*)d_in[15];
    const float* sigmaW = (const float*)d_in[16];
    const float* sigmab = (const float*)d_in[17];
    float* out = (float*)d_out;

    size_t off = 0;
    char* ws = (char*)d_ws;
    auto alloc = [&](size_t bytes) { void* p = ws + off; off += (bytes + 255) & ~(size_t)255; return p; };
    __bf16* XWb  = (__bf16*)alloc((size_t)Bn*TM1*512*2);
    __bf16* Xbf  = (__bf16*)alloc((size_t)Bn*TM1*512*2);
    __bf16* Wdc  = (__bf16*)alloc((size_t)512*1024*2);
    __bf16* W1x  = (__bf16*)alloc((size_t)512*512*2);
    __bf16* Whh  = (__bf16*)alloc((size_t)2048*512*2);
    __bf16* dcb  = (__bf16*)alloc((size_t)Bn*1024*2);
    float*  cf   = (float*)alloc((size_t)Bn*512*4);
    float*  df   = (float*)alloc((size_t)Bn*512*4);
    __bf16* dcWp = (__bf16*)alloc((size_t)4*512*512*2);
    __bf16* dWhhp= (__bf16*)alloc((size_t)2*512*2048*2);
    float*  bsum = (float*)alloc((size_t)2048*4);
    float*  XF   = (float*)alloc((size_t)Bn*TM1*4);
    float*  b62  = (float*)alloc((size_t)Bn*64*4);

    hipMemsetAsync(dcb, 0, (size_t)Bn*1024*2, stream);
    hipMemsetAsync(cf,  0, (size_t)Bn*512*4, stream);

    k_prep_weights<<<512, 256, 0, stream>>>(W1, W_hh_f, b_ih, b_hh, Wdc, W1x, Whh, bsum);
    k_conv_xf<<<(Bn*TM1 + 3)/4, 256, 0, stream>>>(X, fcW, Xbf, XF);
    k_gemm_xw<<<(Bn*TM1/128)*8, 256, 0, stream>>>(Xbf, W1x, b1, XWb);

    for (int t = 0; t < TM1; ++t) {
        k_step_gemm<<<768, 256, 0, stream>>>(dcb, Wdc, Whh, dcWp, dWhhp);
        k_step_fused<<<Bn, 512, 0, stream>>>(t, dcWp, dWhhp, XWb, XF, y_prev, W2,
                                             fcW, fcb, W_ih, bsum,
                                             cf, df, dcb, b62);
    }
    k_finish<<<Bn, 512, 0, stream>>>(b62, Xbf, df,
                                     betaW, betab, sigmaW, sigmab, gammaW, gammab, out);
}